// Round 10
// baseline (165.450 us; speedup 1.0000x reference)
//
#include <hip/hip_runtime.h>
#include <hip/hip_bf16.h>
#include <hip/hip_fp16.h>

// N3 aggregation: C=64, E=32, H=W=128, K=7, PS=7 (PR=3), WS=13 (WR=6), O=169
#define HW 16384

using u16 = unsigned short;
using u32 = unsigned int;
typedef __attribute__((ext_vector_type(2))) float f32x2;

__device__ __forceinline__ u16 f2h(float f) {
    __half h = __float2half(f);
    return __builtin_bit_cast(u16, h);
}
// acc += a.x*b.x + a.y*b.y  (f16 pairs, f32 accumulate)
__device__ __forceinline__ void dot2acc(float& acc, u32 a, u32 b) {
    asm("v_dot2_f32_f16 %0, %1, %2, %0" : "+v"(acc) : "v"(a), "v"(b));
}
#define SELLO 0x05040100u
#define SELHI 0x07060302u

// ---------------------------------------------------------------------------
// K0: transposes + per-pixel norms. grid 64 x 256. one thread per pixel.
// ---------------------------------------------------------------------------
__global__ __launch_bounds__(256) void k_prep(
        const float* __restrict__ x, const float* __restrict__ xe,
        const float* __restrict__ ye,
        u16* __restrict__ xh, float* __restrict__ xeT,
        float* __restrict__ yeT, float* __restrict__ nx, float* __restrict__ ny) {
    int y = blockIdx.x * 256 + threadIdx.x;

#pragma unroll
    for (int c = 0; c < 64; c++)
        xh[c * HW + y] = f2h(x[c * HW + y]);

    float sx = 0.f, sy = 0.f;
#pragma unroll
    for (int e0 = 0; e0 < 32; e0 += 4) {
        float4 v = make_float4(xe[(e0 + 0) * HW + y], xe[(e0 + 1) * HW + y],
                               xe[(e0 + 2) * HW + y], xe[(e0 + 3) * HW + y]);
        *reinterpret_cast<float4*>(xeT + y * 32 + e0) = v;
        sx += v.x * v.x + v.y * v.y + v.z * v.z + v.w * v.w;
        float4 u = make_float4(ye[(e0 + 0) * HW + y], ye[(e0 + 1) * HW + y],
                               ye[(e0 + 2) * HW + y], ye[(e0 + 3) * HW + y]);
        *reinterpret_cast<float4*>(yeT + y * 32 + e0) = u;
        sy += u.x * u.x + u.y * u.y + u.z * u.z + u.w * u.w;
    }
    nx[y] = sx;
    ny[y] = sy;
}

// ---------------------------------------------------------------------------
// K0b: st[y] = (tinv, tinv*Sy), tinv = exp(-boxsum(lt)/49), Sy = boxsum(ny).
// ---------------------------------------------------------------------------
__global__ __launch_bounds__(256) void k_norms(
        const float* __restrict__ ny, const float* __restrict__ lt,
        float2* __restrict__ st) {
    int y = blockIdx.x * 256 + threadIdx.x;
    int py = y >> 7, px = y & 127;
    float s = 0.f, t = 0.f;
    for (int dy = -3; dy <= 3; dy++)
        for (int dx = -3; dx <= 3; dx++) {
            int yy = py + dy, xx = px + dx;
            if ((unsigned)yy < 128u && (unsigned)xx < 128u) {
                int p = yy * 128 + xx;
                s += ny[p];
                t += lt[p];
            }
        }
    float tinv = __expf(-t * (1.0f / 49.0f));
    st[y] = make_float2(tinv, tinv * s);
}

// ---------------------------------------------------------------------------
// K1 v2: logits[o][y] = -tinv*( Sy(y) + boxsum_z( nx(z+o) - 2*ye(z).xe(z+o) ) ).
// grid (13 di, 64 tiles of 16x16), 1024 threads. (unchanged)
// ---------------------------------------------------------------------------
__global__ __launch_bounds__(1024) void k_logits(
        const float* __restrict__ xeT, const float* __restrict__ yeT,
        const float* __restrict__ nxg, const float2* __restrict__ st,
        float* __restrict__ logits) {
#pragma clang fp contract(fast)
    __shared__ __align__(16) char arena[123904];
    float* s_xe = (float*)arena;              // 748 cells * 32 dw, swizzled
    float* s_nx = (float*)(arena + 95744);    // 748
    float* s_d2 = (float*)(arena + 98736);    // 13 * 484
    float* s_hs = (float*)arena;              // overlay after compute: 13*22*16

    int di = blockIdx.x;
    int tile = blockIdx.y;
    int h0 = (tile >> 3) * 16, w0 = (tile & 7) * 16;
    int gr0 = h0 + di - 9, gc0 = w0 - 9;
    int tid = threadIdx.x;

    for (int idx = tid; idx < 748 * 8; idx += 1024) {
        int cell = idx >> 3, q = idx & 7;
        int r = cell / 34, c = cell - r * 34;
        int gy = gr0 + r, gx = gc0 + c;
        float4 v = make_float4(0.f, 0.f, 0.f, 0.f);
        if ((unsigned)gy < 128u && (unsigned)gx < 128u)
            v = *reinterpret_cast<const float4*>(xeT + (size_t)(gy * 128 + gx) * 32 + q * 4);
        *reinterpret_cast<float4*>(s_xe + cell * 32 + ((q ^ (cell & 7)) << 2)) = v;
    }
    for (int idx = tid; idx < 748; idx += 1024) {
        int r = idx / 34, c = idx - r * 34;
        int gy = gr0 + r, gx = gc0 + c;
        float v = 0.f;
        if ((unsigned)gy < 128u && (unsigned)gx < 128u) v = nxg[gy * 128 + gx];
        s_nx[idx] = v;
    }
    __syncthreads();

    if (tid < 484) {
        int zr = tid / 22, zc = tid - zr * 22;
        int gy = h0 - 3 + zr, gx = w0 - 3 + zc;
        bool zin = ((unsigned)gy < 128u) && ((unsigned)gx < 128u);
        f32x2 yv[16];
#pragma unroll
        for (int j = 0; j < 16; j++) yv[j] = (f32x2){0.f, 0.f};
        if (zin) {
            const float* yp = yeT + (size_t)(gy * 128 + gx) * 32;
#pragma unroll
            for (int j = 0; j < 8; j++) {
                float4 t = *reinterpret_cast<const float4*>(yp + j * 4);
                yv[2 * j] = (f32x2){t.x, t.y};
                yv[2 * j + 1] = (f32x2){t.z, t.w};
            }
        }
        int cell0 = zr * 34 + zc;
#pragma unroll
        for (int dj = 0; dj < 13; dj++) {
            int cell = cell0 + dj;
            const float* bp = s_xe + cell * 32;
            int sw = cell & 7;
            f32x2 a0 = {0.f, 0.f}, a1 = {0.f, 0.f};
#pragma unroll
            for (int q = 0; q < 8; q++) {
                float4 xv = *reinterpret_cast<const float4*>(bp + ((q ^ sw) << 2));
                a0 += ((f32x2){xv.x, xv.y}) * yv[2 * q];
                a1 += ((f32x2){xv.z, xv.w}) * yv[2 * q + 1];
            }
            float cr = a0.x + a0.y + a1.x + a1.y;
            float d2v = fmaf(-2.f, cr, s_nx[cell]);
            s_d2[dj * 484 + tid] = zin ? d2v : 0.f;
        }
    }
    __syncthreads();

    for (int idx = tid; idx < 4576; idx += 1024) {
        int dj = idx / 352, rem = idx - dj * 352;
        int r = rem >> 4, c = rem & 15;
        const float* p = s_d2 + dj * 484 + r * 22 + c;
        float s = p[0] + p[1] + p[2] + p[3] + p[4] + p[5] + p[6];
        s_hs[(dj * 22 + r) * 16 + c] = s;
    }
    __syncthreads();

    for (int idx = tid; idx < 3328; idx += 1024) {
        int dj = idx >> 8, rem = idx & 255;
        int i = rem >> 4, jj = rem & 15;
        const float* p = s_hs + (dj * 22 + i) * 16 + jj;
        float s = p[0] + p[16] + p[32] + p[48] + p[64] + p[80] + p[96];
        int y = (h0 + i) * 128 + (w0 + jj);
        float2 ab = st[y];
        logits[(di * 13 + dj) * HW + y] = -fmaf(ab.x, s, ab.y);
    }
}

// ---------------------------------------------------------------------------
// K2: K=7 rounds of exclusion softmax over O=169. grid 512 x 256. (unchanged)
// ---------------------------------------------------------------------------
__global__ __launch_bounds__(256) void k_softmax(
        const float* __restrict__ logits, u16* __restrict__ Wkt) {
    __shared__ float s_lg[169 * 34];
    int tid = threadIdx.x;
    int y0 = blockIdx.x * 32;
    for (int idx = tid; idx < 169 * 32; idx += 256) {
        int o = idx >> 5, p = idx & 31;
        s_lg[o * 34 + p] = logits[o * HW + y0 + p];
    }
    __syncthreads();
    int pix = tid >> 3, t = tid & 7;
    int y = y0 + pix;
    float l[22];
#pragma unroll
    for (int j = 0; j < 22; j++) {
        int o = t + 8 * j;
        l[j] = (o < 169) ? s_lg[o * 34 + pix] : -3e38f;
    }
    u32 wp0[22], wp1[22], wp2[22], wp3[22];
#pragma unroll
    for (int j = 0; j < 22; j++) { wp0[j] = 0u; wp1[j] = 0u; wp2[j] = 0u; wp3[j] = 0u; }

    float e[22];
#pragma unroll
    for (int k = 0; k < 7; k++) {
        float m = -3e38f;
#pragma unroll
        for (int j = 0; j < 22; j++) m = fmaxf(m, l[j]);
        m = fmaxf(m, __shfl_xor(m, 1));
        m = fmaxf(m, __shfl_xor(m, 2));
        m = fmaxf(m, __shfl_xor(m, 4));
        float s = 0.f;
#pragma unroll
        for (int j = 0; j < 22; j++) { e[j] = __expf(l[j] - m); s += e[j]; }
        s += __shfl_xor(s, 1);
        s += __shfl_xor(s, 2);
        s += __shfl_xor(s, 4);
        float rs = 1.0f / s;
#pragma unroll
        for (int j = 0; j < 22; j++) {
            float w = e[j] * rs;
            u32 h = (u32)f2h(w);
            if (k == 0) wp0[j] |= h;
            else if (k == 1) wp0[j] |= h << 16;
            else if (k == 2) wp1[j] |= h;
            else if (k == 3) wp1[j] |= h << 16;
            else if (k == 4) wp2[j] |= h;
            else if (k == 5) wp2[j] |= h << 16;
            else wp3[j] |= h;
            if (k < 6) l[j] += __logf(fmaxf(1.0f - w, 1e-6f));
        }
    }
#pragma unroll
    for (int j = 0; j < 22; j++) {
        int o = t + 8 * j;
        if (o < 169)
            *reinterpret_cast<uint4*>(Wkt + (o * HW + y) * 8) =
                make_uint4(wp0[j], wp1[j], wp2[j], wp3[j]);
    }
}

// ---------------------------------------------------------------------------
// K2b v2: 7x7 boxsum of Wkt(f16) -> PAIR-PACKED WsP[o2][y][8 u32],
// u32[k] = (f16 w(di,2djp,k) , f16 w(di,2djp+1,k)); slot 7 = 0. (unchanged)
// ---------------------------------------------------------------------------
__global__ __launch_bounds__(256) void k_wsum(
        const u16* __restrict__ Wkt, u32* __restrict__ WsP) {
    __shared__ u16 s_w[38 * 39 * 8];   // [row][col pad39][k8]
    __shared__ u16 s_v[32 * 38 * 8];   // [outrow][col][k8] f16 vertical sums
    int o2 = blockIdx.x;
    int di = o2 / 7, djp = o2 - di * 7;
    int oA = di * 13 + 2 * djp;
    bool hasB = (djp < 6);
    int tile = blockIdx.y;
    int h0 = (tile >> 2) * 32, w0 = (tile & 3) * 32;
    int tid = threadIdx.x;

    auto stage = [&](int o) {
        const u16* src = Wkt + (size_t)o * (HW * 8);
        for (int idx = tid; idx < 38 * 38; idx += 256) {
            int r = idx / 38, c = idx - r * 38;
            int gy = h0 - 3 + r, gx = w0 - 3 + c;
            uint4 v = make_uint4(0u, 0u, 0u, 0u);
            if ((unsigned)gy < 128u && (unsigned)gx < 128u)
                v = *reinterpret_cast<const uint4*>(src + (gy * 128 + gx) * 8);
            *reinterpret_cast<uint4*>(s_w + (r * 39 + c) * 8) = v;
        }
    };
    auto vert = [&]() {
        for (int u = tid; u < 1216; u += 256) {   // 32 out-rows x 38 cols
            int r = u / 38, c = u - r * 38;
            __half2 s0 = __builtin_bit_cast(__half2, 0u);
            __half2 s1 = s0, s2 = s0, s3 = s0;
#pragma unroll
            for (int d = 0; d < 7; d++) {
                uint4 q = *reinterpret_cast<const uint4*>(s_w + ((r + d) * 39 + c) * 8);
                s0 = __hadd2(s0, __builtin_bit_cast(__half2, q.x));
                s1 = __hadd2(s1, __builtin_bit_cast(__half2, q.y));
                s2 = __hadd2(s2, __builtin_bit_cast(__half2, q.z));
                s3 = __hadd2(s3, __builtin_bit_cast(__half2, q.w));
            }
            *reinterpret_cast<uint4*>(s_v + (r * 38 + c) * 8) = make_uint4(
                __builtin_bit_cast(u32, s0), __builtin_bit_cast(u32, s1),
                __builtin_bit_cast(u32, s2), __builtin_bit_cast(u32, s3));
        }
    };
    auto horiz = [&](uint4 (&rr)[4]) {
#pragma unroll
        for (int i = 0; i < 4; i++) {              // 32 rows x 32 out-cols
            int u = tid + i * 256;
            int r = u >> 5, cx = u & 31;
            __half2 s0 = __builtin_bit_cast(__half2, 0u);
            __half2 s1 = s0, s2 = s0, s3 = s0;
#pragma unroll
            for (int d = 0; d < 7; d++) {
                uint4 q = *reinterpret_cast<const uint4*>(s_v + (r * 38 + cx + d) * 8);
                s0 = __hadd2(s0, __builtin_bit_cast(__half2, q.x));
                s1 = __hadd2(s1, __builtin_bit_cast(__half2, q.y));
                s2 = __hadd2(s2, __builtin_bit_cast(__half2, q.z));
                s3 = __hadd2(s3, __builtin_bit_cast(__half2, q.w));
            }
            rr[i] = make_uint4(
                __builtin_bit_cast(u32, s0), __builtin_bit_cast(u32, s1),
                __builtin_bit_cast(u32, s2), __builtin_bit_cast(u32, s3));
        }
    };

    uint4 rA[4], rB[4];
#pragma unroll
    for (int i = 0; i < 4; i++) rB[i] = make_uint4(0u, 0u, 0u, 0u);

    stage(oA);
    __syncthreads();
    vert();
    __syncthreads();
    horiz(rA);
    if (hasB) {
        __syncthreads();           // rA-horiz reads done; safe to overwrite s_w
        stage(oA + 1);
        __syncthreads();
        vert();
        __syncthreads();
        horiz(rB);
    }

#pragma unroll
    for (int i = 0; i < 4; i++) {
        int u = tid + i * 256;
        int r = u >> 5, cx = u & 31;
        int y = (h0 + r) * 128 + (w0 + cx);
        u32* dst = WsP + ((size_t)o2 * HW + y) * 8;
        uint4 lo = make_uint4(
            __builtin_amdgcn_perm(rB[i].x, rA[i].x, SELLO),
            __builtin_amdgcn_perm(rB[i].x, rA[i].x, SELHI),
            __builtin_amdgcn_perm(rB[i].y, rA[i].y, SELLO),
            __builtin_amdgcn_perm(rB[i].y, rA[i].y, SELHI));
        uint4 hi = make_uint4(
            __builtin_amdgcn_perm(rB[i].z, rA[i].z, SELLO),
            __builtin_amdgcn_perm(rB[i].z, rA[i].z, SELHI),
            __builtin_amdgcn_perm(rB[i].w, rA[i].w, SELLO),
            0u);
        *reinterpret_cast<uint4*>(dst) = lo;
        *reinterpret_cast<uint4*>(dst + 4) = hi;
    }
}

// ---------------------------------------------------------------------------
// K3 v9: aggregation. v8 structure + WAVE REMAP so the 8 lanes sharing a
// pixel are adjacent (W loads become 8-way same-address broadcast, 2 cache
// lines/instr: L1 W traffic 745KB -> 186KB per block) + bank-exact LDS
// (plane stride 226 dw: cc-step 904 dw = 8 mod 32, pc spreads remaining
// banks -> <=2-way, free). grid 512 tiles (2x16 pix); 512 thr = 32 pix x
// 16 cc (4ch). Keeps di ping-pong W prefetch + reg-dbuf x reads.
// ---------------------------------------------------------------------------
__global__ __launch_bounds__(512, 2) void k_agg(
        const u16* __restrict__ xh, const u32* __restrict__ WsP,
        float* __restrict__ out) {
    __shared__ u16 s_x[64 * 452];       // [ch][14r][32c], plane 452 u16 = 226 dw
    int tb = blockIdx.x;                // 64 row-tiles x 8 col-tiles
    int h0 = (tb >> 3) * 2, w0 = (tb & 7) * 16;
    int tid = threadIdx.x;

    // stage: 3584 units = 64ch x 14r x 4 chunks of 8 cols (7 x 512 exact)
#pragma unroll
    for (int i = 0; i < 7; i++) {
        int it = tid + i * 512;
        int ch = it / 56, rem = it - ch * 56;
        int r = rem >> 2, j = rem & 3;
        int gy = h0 - 6 + r, gx0 = w0 - 6 + 8 * j;
        uint4 v = make_uint4(0u, 0u, 0u, 0u);
        if ((unsigned)gy < 128u) {
            const u16* src = xh + (size_t)ch * HW + gy * 128;
            if (gx0 >= 0 && gx0 <= 120) {
                v = *reinterpret_cast<const uint4*>(src + gx0);
            } else {
                auto pk = [&](int gx) -> u32 {
                    u32 lo = ((unsigned)gx < 128u) ? (u32)src[gx] : 0u;
                    u32 hi = ((unsigned)(gx + 1) < 128u) ? (u32)src[gx + 1] : 0u;
                    return lo | (hi << 16);
                };
                v = make_uint4(pk(gx0), pk(gx0 + 2), pk(gx0 + 4), pk(gx0 + 6));
            }
        }
        u16* dst = s_x + ch * 452 + r * 32 + 8 * j;   // 8B-aligned (452%4==0)
        *reinterpret_cast<uint2*>(dst) = make_uint2(v.x, v.y);
        *reinterpret_cast<uint2*>(dst + 4) = make_uint2(v.z, v.w);
    }
    __syncthreads();

    // lane map: wave = 8 consecutive pixels x 8 cc -> W same-addr broadcast
    int w = tid >> 6, l = tid & 63;
    int pl = l >> 3, cl = l & 7;
    int pix = (w & 3) * 8 + pl;         // 0..31
    int cc  = (w >> 2) * 8 + cl;        // 0..15 (4 ch each)
    int pr = pix >> 4, pc = pix & 15;
    int y = (h0 + pr) * 128 + (w0 + pc);
    const u32* wsrc = WsP + (size_t)y * 8;
    const u32* s_x32 = reinterpret_cast<const u32*>(s_x);
    u32 sh = (u32)(pc & 1) * 16;
    int base0 = cc * 904 + (pc >> 1);   // dwords; + q*226 + (pr+di)*16

    float acc[7][4];
#pragma unroll
    for (int k = 0; k < 7; k++)
#pragma unroll
        for (int q = 0; q < 4; q++) acc[k][q] = 0.f;

    auto loadW = [&](int di, uint4 (&A)[7], uint4 (&B)[7]) {
        const u32* wdi = wsrc + (size_t)(di * 7) * (HW * 8);
#pragma unroll
        for (int djp = 0; djp < 7; djp++) {
            const u32* wp = wdi + (size_t)djp * (HW * 8);
            A[djp] = *reinterpret_cast<const uint4*>(wp);
            B[djp] = *reinterpret_cast<const uint4*>(wp + 4);
        }
    };
    auto loadX = [&](u32 (&buf)[8], int dwoff) {
        const u32* p = s_x32 + dwoff;
#pragma unroll
        for (int j = 0; j < 8; j++) buf[j] = p[j];
    };
    auto computeQ = [&](const u32 (&f)[8], const uint4 (&A)[7],
                        const uint4 (&B)[7], int q) {
#pragma unroll
        for (int djp = 0; djp < 7; djp++) {
            u32 x2 = __builtin_amdgcn_alignbit(f[djp + 1], f[djp], sh);
            dot2acc(acc[0][q], A[djp].x, x2);
            dot2acc(acc[1][q], A[djp].y, x2);
            dot2acc(acc[2][q], A[djp].z, x2);
            dot2acc(acc[3][q], A[djp].w, x2);
            dot2acc(acc[4][q], B[djp].x, x2);
            dot2acc(acc[5][q], B[djp].y, x2);
            dot2acc(acc[6][q], B[djp].z, x2);
        }
    };
    // register-double-buffered q sweep; leaves xb = next di's plane-0 row
    auto computeDi = [&](int di, int nextdi, const uint4 (&A)[7],
                         const uint4 (&B)[7], u32 (&xb)[8], u32 (&xt)[8]) {
        int ro = base0 + (pr + di) * 16;
        loadX(xt, ro + 226);                          // q=1
        computeQ(xb, A, B, 0);
        loadX(xb, ro + 2 * 226);                      // q=2
        computeQ(xt, A, B, 1);
        loadX(xt, ro + 3 * 226);                      // q=3
        computeQ(xb, A, B, 2);
        loadX(xb, base0 + (pr + nextdi) * 16);        // next di, q=0
        computeQ(xt, A, B, 3);
    };

    uint4 WA[7], WB[7], WC[7], WD[7];
    u32 xb[8], xt[8];
    loadW(0, WA, WB);
    loadX(xb, base0 + pr * 16);
#pragma unroll 1
    for (int di = 0; di < 12; di += 2) {
        loadW(di + 1, WC, WD);     // prefetch next di's W while computing
        computeDi(di, di + 1, WA, WB, xb, xt);
        loadW(di + 2, WA, WB);     // di+2 <= 12 always inside this loop
        computeDi(di + 1, di + 2, WC, WD, xb, xt);
    }
    computeDi(12, 12, WA, WB, xb, xt);

#pragma unroll
    for (int k = 0; k < 7; k++)
#pragma unroll
        for (int q = 0; q < 4; q++)
            out[(k * 64 + cc * 4 + q) * HW + y] = acc[k][q];
}

// ---------------------------------------------------------------------------
extern "C" void kernel_launch(void* const* d_in, const int* in_sizes, int n_in,
                              void* d_out, int out_size, void* d_ws, size_t ws_size,
                              hipStream_t stream) {
    (void)in_sizes; (void)n_in; (void)out_size; (void)ws_size;
    const float* x  = (const float*)d_in[0];
    const float* xe = (const float*)d_in[1];
    const float* ye = (const float*)d_in[2];
    const float* lt = (const float*)d_in[3];
    float* out = (float*)d_out;
    char* ws = (char*)d_ws;

    // layout (98.3 MB total):
    u16*   xh     = (u16*)(ws + 0);            //  2,097,152 B (f16 [64][128][128])
    float* xeT    = (float*)(ws + 2097152u);   //  2,097,152
    float* yeT    = (float*)(ws + 4194304u);   //  2,097,152
    u16*   Wkt    = (u16*)(ws + 6291456u);     // 44,302,336 -> 50,593,792
    float* logits = (float*)(ws + 50593792u);  // 11,075,584 (dead after k_softmax)
    u32*   WsP    = (u32*)(ws + 50593792u);    // 47,710,208 -> 98,304,000 (overlays logits)
    // nx/ny/st overlay Wkt head: written by k_prep/k_norms, last read by
    // k_logits; Wkt is written later by k_softmax.
    float*  nx = (float*)(ws + 6291456u);             // 65,536
    float*  ny = (float*)(ws + 6291456u + 65536u);    // 65,536
    float2* st = (float2*)(ws + 6291456u + 131072u);  // 131,072

    k_prep<<<64, 256, 0, stream>>>(x, xe, ye, xh, xeT, yeT, nx, ny);
    k_norms<<<64, 256, 0, stream>>>(ny, lt, st);
    k_logits<<<dim3(13, 64), 1024, 0, stream>>>(xeT, yeT, nx, st, logits);
    k_softmax<<<512, 256, 0, stream>>>(logits, Wkt);
    k_wsum<<<dim3(91, 16), 256, 0, stream>>>(Wkt, WsP);
    k_agg<<<512, 512, 0, stream>>>(xh, WsP, out);
}

// Round 11
// 159.767 us; speedup vs baseline: 1.0356x; 1.0356x over previous
//
#include <hip/hip_runtime.h>
#include <hip/hip_bf16.h>
#include <hip/hip_fp16.h>

// N3 aggregation: C=64, E=32, H=W=128, K=7, PS=7 (PR=3), WS=13 (WR=6), O=169
#define HW 16384

using u16 = unsigned short;
using u32 = unsigned int;
typedef __attribute__((ext_vector_type(2))) float f32x2;

__device__ __forceinline__ u16 f2h(float f) {
    __half h = __float2half(f);
    return __builtin_bit_cast(u16, h);
}
// acc += a.x*b.x + a.y*b.y  (f16 pairs, f32 accumulate)
__device__ __forceinline__ void dot2acc(float& acc, u32 a, u32 b) {
    asm("v_dot2_f32_f16 %0, %1, %2, %0" : "+v"(acc) : "v"(a), "v"(b));
}
#define SELLO 0x05040100u
#define SELHI 0x07060302u

// ---------------------------------------------------------------------------
// K0: transposes + per-pixel norms. grid 64 x 256. one thread per pixel.
// ---------------------------------------------------------------------------
__global__ __launch_bounds__(256) void k_prep(
        const float* __restrict__ x, const float* __restrict__ xe,
        const float* __restrict__ ye,
        u16* __restrict__ xh, float* __restrict__ xeT,
        float* __restrict__ yeT, float* __restrict__ nx, float* __restrict__ ny) {
    int y = blockIdx.x * 256 + threadIdx.x;

#pragma unroll
    for (int c = 0; c < 64; c++)
        xh[c * HW + y] = f2h(x[c * HW + y]);

    float sx = 0.f, sy = 0.f;
#pragma unroll
    for (int e0 = 0; e0 < 32; e0 += 4) {
        float4 v = make_float4(xe[(e0 + 0) * HW + y], xe[(e0 + 1) * HW + y],
                               xe[(e0 + 2) * HW + y], xe[(e0 + 3) * HW + y]);
        *reinterpret_cast<float4*>(xeT + y * 32 + e0) = v;
        sx += v.x * v.x + v.y * v.y + v.z * v.z + v.w * v.w;
        float4 u = make_float4(ye[(e0 + 0) * HW + y], ye[(e0 + 1) * HW + y],
                               ye[(e0 + 2) * HW + y], ye[(e0 + 3) * HW + y]);
        *reinterpret_cast<float4*>(yeT + y * 32 + e0) = u;
        sy += u.x * u.x + u.y * u.y + u.z * u.z + u.w * u.w;
    }
    nx[y] = sx;
    ny[y] = sy;
}

// ---------------------------------------------------------------------------
// K0b: st[y] = (tinv, tinv*Sy), tinv = exp(-boxsum(lt)/49), Sy = boxsum(ny).
// ---------------------------------------------------------------------------
__global__ __launch_bounds__(256) void k_norms(
        const float* __restrict__ ny, const float* __restrict__ lt,
        float2* __restrict__ st) {
    int y = blockIdx.x * 256 + threadIdx.x;
    int py = y >> 7, px = y & 127;
    float s = 0.f, t = 0.f;
    for (int dy = -3; dy <= 3; dy++)
        for (int dx = -3; dx <= 3; dx++) {
            int yy = py + dy, xx = px + dx;
            if ((unsigned)yy < 128u && (unsigned)xx < 128u) {
                int p = yy * 128 + xx;
                s += ny[p];
                t += lt[p];
            }
        }
    float tinv = __expf(-t * (1.0f / 49.0f));
    st[y] = make_float2(tinv, tinv * s);
}

// ---------------------------------------------------------------------------
// K1 v2: logits[o][y] = -tinv*( Sy(y) + boxsum_z( nx(z+o) - 2*ye(z).xe(z+o) ) ).
// grid (13 di, 64 tiles of 16x16), 1024 threads. (unchanged)
// ---------------------------------------------------------------------------
__global__ __launch_bounds__(1024) void k_logits(
        const float* __restrict__ xeT, const float* __restrict__ yeT,
        const float* __restrict__ nxg, const float2* __restrict__ st,
        float* __restrict__ logits) {
#pragma clang fp contract(fast)
    __shared__ __align__(16) char arena[123904];
    float* s_xe = (float*)arena;              // 748 cells * 32 dw, swizzled
    float* s_nx = (float*)(arena + 95744);    // 748
    float* s_d2 = (float*)(arena + 98736);    // 13 * 484
    float* s_hs = (float*)arena;              // overlay after compute: 13*22*16

    int di = blockIdx.x;
    int tile = blockIdx.y;
    int h0 = (tile >> 3) * 16, w0 = (tile & 7) * 16;
    int gr0 = h0 + di - 9, gc0 = w0 - 9;
    int tid = threadIdx.x;

    for (int idx = tid; idx < 748 * 8; idx += 1024) {
        int cell = idx >> 3, q = idx & 7;
        int r = cell / 34, c = cell - r * 34;
        int gy = gr0 + r, gx = gc0 + c;
        float4 v = make_float4(0.f, 0.f, 0.f, 0.f);
        if ((unsigned)gy < 128u && (unsigned)gx < 128u)
            v = *reinterpret_cast<const float4*>(xeT + (size_t)(gy * 128 + gx) * 32 + q * 4);
        *reinterpret_cast<float4*>(s_xe + cell * 32 + ((q ^ (cell & 7)) << 2)) = v;
    }
    for (int idx = tid; idx < 748; idx += 1024) {
        int r = idx / 34, c = idx - r * 34;
        int gy = gr0 + r, gx = gc0 + c;
        float v = 0.f;
        if ((unsigned)gy < 128u && (unsigned)gx < 128u) v = nxg[gy * 128 + gx];
        s_nx[idx] = v;
    }
    __syncthreads();

    if (tid < 484) {
        int zr = tid / 22, zc = tid - zr * 22;
        int gy = h0 - 3 + zr, gx = w0 - 3 + zc;
        bool zin = ((unsigned)gy < 128u) && ((unsigned)gx < 128u);
        f32x2 yv[16];
#pragma unroll
        for (int j = 0; j < 16; j++) yv[j] = (f32x2){0.f, 0.f};
        if (zin) {
            const float* yp = yeT + (size_t)(gy * 128 + gx) * 32;
#pragma unroll
            for (int j = 0; j < 8; j++) {
                float4 t = *reinterpret_cast<const float4*>(yp + j * 4);
                yv[2 * j] = (f32x2){t.x, t.y};
                yv[2 * j + 1] = (f32x2){t.z, t.w};
            }
        }
        int cell0 = zr * 34 + zc;
#pragma unroll
        for (int dj = 0; dj < 13; dj++) {
            int cell = cell0 + dj;
            const float* bp = s_xe + cell * 32;
            int sw = cell & 7;
            f32x2 a0 = {0.f, 0.f}, a1 = {0.f, 0.f};
#pragma unroll
            for (int q = 0; q < 8; q++) {
                float4 xv = *reinterpret_cast<const float4*>(bp + ((q ^ sw) << 2));
                a0 += ((f32x2){xv.x, xv.y}) * yv[2 * q];
                a1 += ((f32x2){xv.z, xv.w}) * yv[2 * q + 1];
            }
            float cr = a0.x + a0.y + a1.x + a1.y;
            float d2v = fmaf(-2.f, cr, s_nx[cell]);
            s_d2[dj * 484 + tid] = zin ? d2v : 0.f;
        }
    }
    __syncthreads();

    for (int idx = tid; idx < 4576; idx += 1024) {
        int dj = idx / 352, rem = idx - dj * 352;
        int r = rem >> 4, c = rem & 15;
        const float* p = s_d2 + dj * 484 + r * 22 + c;
        float s = p[0] + p[1] + p[2] + p[3] + p[4] + p[5] + p[6];
        s_hs[(dj * 22 + r) * 16 + c] = s;
    }
    __syncthreads();

    for (int idx = tid; idx < 3328; idx += 1024) {
        int dj = idx >> 8, rem = idx & 255;
        int i = rem >> 4, jj = rem & 15;
        const float* p = s_hs + (dj * 22 + i) * 16 + jj;
        float s = p[0] + p[16] + p[32] + p[48] + p[64] + p[80] + p[96];
        int y = (h0 + i) * 128 + (w0 + jj);
        float2 ab = st[y];
        logits[(di * 13 + dj) * HW + y] = -fmaf(ab.x, s, ab.y);
    }
}

// ---------------------------------------------------------------------------
// K2: K=7 rounds of exclusion softmax over O=169. grid 512 x 256. (unchanged)
// ---------------------------------------------------------------------------
__global__ __launch_bounds__(256) void k_softmax(
        const float* __restrict__ logits, u16* __restrict__ Wkt) {
    __shared__ float s_lg[169 * 34];
    int tid = threadIdx.x;
    int y0 = blockIdx.x * 32;
    for (int idx = tid; idx < 169 * 32; idx += 256) {
        int o = idx >> 5, p = idx & 31;
        s_lg[o * 34 + p] = logits[o * HW + y0 + p];
    }
    __syncthreads();
    int pix = tid >> 3, t = tid & 7;
    int y = y0 + pix;
    float l[22];
#pragma unroll
    for (int j = 0; j < 22; j++) {
        int o = t + 8 * j;
        l[j] = (o < 169) ? s_lg[o * 34 + pix] : -3e38f;
    }
    u32 wp0[22], wp1[22], wp2[22], wp3[22];
#pragma unroll
    for (int j = 0; j < 22; j++) { wp0[j] = 0u; wp1[j] = 0u; wp2[j] = 0u; wp3[j] = 0u; }

    float e[22];
#pragma unroll
    for (int k = 0; k < 7; k++) {
        float m = -3e38f;
#pragma unroll
        for (int j = 0; j < 22; j++) m = fmaxf(m, l[j]);
        m = fmaxf(m, __shfl_xor(m, 1));
        m = fmaxf(m, __shfl_xor(m, 2));
        m = fmaxf(m, __shfl_xor(m, 4));
        float s = 0.f;
#pragma unroll
        for (int j = 0; j < 22; j++) { e[j] = __expf(l[j] - m); s += e[j]; }
        s += __shfl_xor(s, 1);
        s += __shfl_xor(s, 2);
        s += __shfl_xor(s, 4);
        float rs = 1.0f / s;
#pragma unroll
        for (int j = 0; j < 22; j++) {
            float w = e[j] * rs;
            u32 h = (u32)f2h(w);
            if (k == 0) wp0[j] |= h;
            else if (k == 1) wp0[j] |= h << 16;
            else if (k == 2) wp1[j] |= h;
            else if (k == 3) wp1[j] |= h << 16;
            else if (k == 4) wp2[j] |= h;
            else if (k == 5) wp2[j] |= h << 16;
            else wp3[j] |= h;
            if (k < 6) l[j] += __logf(fmaxf(1.0f - w, 1e-6f));
        }
    }
#pragma unroll
    for (int j = 0; j < 22; j++) {
        int o = t + 8 * j;
        if (o < 169)
            *reinterpret_cast<uint4*>(Wkt + (o * HW + y) * 8) =
                make_uint4(wp0[j], wp1[j], wp2[j], wp3[j]);
    }
}

// ---------------------------------------------------------------------------
// K2b v2: 7x7 boxsum of Wkt(f16) -> PAIR-PACKED WsP[o2][y][8 u32],
// u32[k] = (f16 w(di,2djp,k) , f16 w(di,2djp+1,k)); slot 7 = 0. (unchanged)
// ---------------------------------------------------------------------------
__global__ __launch_bounds__(256) void k_wsum(
        const u16* __restrict__ Wkt, u32* __restrict__ WsP) {
    __shared__ u16 s_w[38 * 39 * 8];   // [row][col pad39][k8]
    __shared__ u16 s_v[32 * 38 * 8];   // [outrow][col][k8] f16 vertical sums
    int o2 = blockIdx.x;
    int di = o2 / 7, djp = o2 - di * 7;
    int oA = di * 13 + 2 * djp;
    bool hasB = (djp < 6);
    int tile = blockIdx.y;
    int h0 = (tile >> 2) * 32, w0 = (tile & 3) * 32;
    int tid = threadIdx.x;

    auto stage = [&](int o) {
        const u16* src = Wkt + (size_t)o * (HW * 8);
        for (int idx = tid; idx < 38 * 38; idx += 256) {
            int r = idx / 38, c = idx - r * 38;
            int gy = h0 - 3 + r, gx = w0 - 3 + c;
            uint4 v = make_uint4(0u, 0u, 0u, 0u);
            if ((unsigned)gy < 128u && (unsigned)gx < 128u)
                v = *reinterpret_cast<const uint4*>(src + (gy * 128 + gx) * 8);
            *reinterpret_cast<uint4*>(s_w + (r * 39 + c) * 8) = v;
        }
    };
    auto vert = [&]() {
        for (int u = tid; u < 1216; u += 256) {   // 32 out-rows x 38 cols
            int r = u / 38, c = u - r * 38;
            __half2 s0 = __builtin_bit_cast(__half2, 0u);
            __half2 s1 = s0, s2 = s0, s3 = s0;
#pragma unroll
            for (int d = 0; d < 7; d++) {
                uint4 q = *reinterpret_cast<const uint4*>(s_w + ((r + d) * 39 + c) * 8);
                s0 = __hadd2(s0, __builtin_bit_cast(__half2, q.x));
                s1 = __hadd2(s1, __builtin_bit_cast(__half2, q.y));
                s2 = __hadd2(s2, __builtin_bit_cast(__half2, q.z));
                s3 = __hadd2(s3, __builtin_bit_cast(__half2, q.w));
            }
            *reinterpret_cast<uint4*>(s_v + (r * 38 + c) * 8) = make_uint4(
                __builtin_bit_cast(u32, s0), __builtin_bit_cast(u32, s1),
                __builtin_bit_cast(u32, s2), __builtin_bit_cast(u32, s3));
        }
    };
    auto horiz = [&](uint4 (&rr)[4]) {
#pragma unroll
        for (int i = 0; i < 4; i++) {              // 32 rows x 32 out-cols
            int u = tid + i * 256;
            int r = u >> 5, cx = u & 31;
            __half2 s0 = __builtin_bit_cast(__half2, 0u);
            __half2 s1 = s0, s2 = s0, s3 = s0;
#pragma unroll
            for (int d = 0; d < 7; d++) {
                uint4 q = *reinterpret_cast<const uint4*>(s_v + (r * 38 + cx + d) * 8);
                s0 = __hadd2(s0, __builtin_bit_cast(__half2, q.x));
                s1 = __hadd2(s1, __builtin_bit_cast(__half2, q.y));
                s2 = __hadd2(s2, __builtin_bit_cast(__half2, q.z));
                s3 = __hadd2(s3, __builtin_bit_cast(__half2, q.w));
            }
            rr[i] = make_uint4(
                __builtin_bit_cast(u32, s0), __builtin_bit_cast(u32, s1),
                __builtin_bit_cast(u32, s2), __builtin_bit_cast(u32, s3));
        }
    };

    uint4 rA[4], rB[4];
#pragma unroll
    for (int i = 0; i < 4; i++) rB[i] = make_uint4(0u, 0u, 0u, 0u);

    stage(oA);
    __syncthreads();
    vert();
    __syncthreads();
    horiz(rA);
    if (hasB) {
        __syncthreads();           // rA-horiz reads done; safe to overwrite s_w
        stage(oA + 1);
        __syncthreads();
        vert();
        __syncthreads();
        horiz(rB);
    }

#pragma unroll
    for (int i = 0; i < 4; i++) {
        int u = tid + i * 256;
        int r = u >> 5, cx = u & 31;
        int y = (h0 + r) * 128 + (w0 + cx);
        u32* dst = WsP + ((size_t)o2 * HW + y) * 8;
        uint4 lo = make_uint4(
            __builtin_amdgcn_perm(rB[i].x, rA[i].x, SELLO),
            __builtin_amdgcn_perm(rB[i].x, rA[i].x, SELHI),
            __builtin_amdgcn_perm(rB[i].y, rA[i].y, SELLO),
            __builtin_amdgcn_perm(rB[i].y, rA[i].y, SELHI));
        uint4 hi = make_uint4(
            __builtin_amdgcn_perm(rB[i].z, rA[i].z, SELLO),
            __builtin_amdgcn_perm(rB[i].z, rA[i].z, SELHI),
            __builtin_amdgcn_perm(rB[i].w, rA[i].w, SELLO),
            0u);
        *reinterpret_cast<uint4*>(dst) = lo;
        *reinterpret_cast<uint4*>(dst + 4) = hi;
    }
}

// ---------------------------------------------------------------------------
// K3 v10: aggregation. v7 wave map (proven 0 bank conflicts) + pair-packed
// WsP + reg-dbuf x reads, with 2-way channel split to halve LDS to 32KB so
// 4 blocks/CU can co-reside (v8's 57.9KB capped at 2 -> exposed W latency).
// grid 512 = 256 tiles (4x16 pix) x 2 csplit(32ch); 512 thr = 64 pix x 8 cc.
// s_x [32ch][16r][32c] f16 = 32KB, plane stride 256 dw.
// ---------------------------------------------------------------------------
__global__ __launch_bounds__(512) void k_agg(
        const u16* __restrict__ xh, const u32* __restrict__ WsP,
        float* __restrict__ out) {
    __shared__ u16 s_x[32 * 512];       // [ch][16r][32c] f16, 32KB
    int tb = blockIdx.x & 255;
    int csplit = blockIdx.x >> 8;       // 32 channels per split
    int h0 = (tb >> 3) * 4, w0 = (tb & 7) * 16;
    int tid = threadIdx.x;

    // stage: 2048 units = 32ch x 16r x 4 chunks of 8 cols
#pragma unroll
    for (int i = 0; i < 4; i++) {
        int it = tid + i * 512;
        int ch = it >> 6;
        int r = (it >> 2) & 15;
        int c0 = (it & 3) * 8;
        int gy = h0 - 6 + r, gx0 = w0 - 6 + c0;
        int gc = csplit * 32 + ch;
        uint4 v = make_uint4(0u, 0u, 0u, 0u);
        if ((unsigned)gy < 128u) {
            const u16* src = xh + (size_t)gc * HW + gy * 128;
            if (gx0 >= 0 && gx0 <= 120) {
                v = *reinterpret_cast<const uint4*>(src + gx0);
            } else {
                auto pk = [&](int gx) -> u32 {
                    u32 lo = ((unsigned)gx < 128u) ? (u32)src[gx] : 0u;
                    u32 hi = ((unsigned)(gx + 1) < 128u) ? (u32)src[gx + 1] : 0u;
                    return lo | (hi << 16);
                };
                v = make_uint4(pk(gx0), pk(gx0 + 2), pk(gx0 + 4), pk(gx0 + 6));
            }
        }
        *reinterpret_cast<uint4*>(s_x + (ch * 16 + r) * 32 + c0) = v;
    }
    __syncthreads();

    int cc = tid >> 6, pix = tid & 63;      // wave = one cc x 64 pixels
    int pr = pix >> 4, pc = pix & 15;
    int y = (h0 + pr) * 128 + (w0 + pc);
    const u32* wsrc = WsP + (size_t)y * 8;
    const u32* s_x32 = reinterpret_cast<const u32*>(s_x);
    u32 sh = (u32)(pc & 1) * 16;
    int base0 = cc * 1024 + (pc >> 1);      // dwords; + q*256 + (pr+di)*16

    float acc[7][4];
#pragma unroll
    for (int k = 0; k < 7; k++)
#pragma unroll
        for (int q = 0; q < 4; q++) acc[k][q] = 0.f;

    auto loadW = [&](int di, uint4 (&A)[7], uint4 (&B)[7]) {
        const u32* wdi = wsrc + (size_t)(di * 7) * (HW * 8);
#pragma unroll
        for (int djp = 0; djp < 7; djp++) {
            const u32* wp = wdi + (size_t)djp * (HW * 8);
            A[djp] = *reinterpret_cast<const uint4*>(wp);
            B[djp] = *reinterpret_cast<const uint4*>(wp + 4);
        }
    };
    auto loadX = [&](u32 (&buf)[8], int dwoff) {
        const u32* p = s_x32 + dwoff;
#pragma unroll
        for (int j = 0; j < 8; j++) buf[j] = p[j];
    };
    auto computeQ = [&](const u32 (&f)[8], const uint4 (&A)[7],
                        const uint4 (&B)[7], int q) {
#pragma unroll
        for (int djp = 0; djp < 7; djp++) {
            u32 x2 = __builtin_amdgcn_alignbit(f[djp + 1], f[djp], sh);
            dot2acc(acc[0][q], A[djp].x, x2);
            dot2acc(acc[1][q], A[djp].y, x2);
            dot2acc(acc[2][q], A[djp].z, x2);
            dot2acc(acc[3][q], A[djp].w, x2);
            dot2acc(acc[4][q], B[djp].x, x2);
            dot2acc(acc[5][q], B[djp].y, x2);
            dot2acc(acc[6][q], B[djp].z, x2);
        }
    };
    // register-double-buffered q sweep; leaves xb = next di's plane-0 row
    auto computeDi = [&](int di, int nextdi, const uint4 (&A)[7],
                         const uint4 (&B)[7], u32 (&xb)[8], u32 (&xt)[8]) {
        int ro = base0 + (pr + di) * 16;
        loadX(xt, ro + 256);                          // q=1
        computeQ(xb, A, B, 0);
        loadX(xb, ro + 512);                          // q=2
        computeQ(xt, A, B, 1);
        loadX(xt, ro + 768);                          // q=3
        computeQ(xb, A, B, 2);
        loadX(xb, base0 + (pr + nextdi) * 16);        // next di, q=0
        computeQ(xt, A, B, 3);
    };

    uint4 WA[7], WB[7], WC[7], WD[7];
    u32 xb[8], xt[8];
    loadW(0, WA, WB);
    loadX(xb, base0 + pr * 16);
#pragma unroll 1
    for (int di = 0; di < 12; di += 2) {
        loadW(di + 1, WC, WD);     // prefetch next di's W while computing
        computeDi(di, di + 1, WA, WB, xb, xt);
        loadW(di + 2, WA, WB);     // di+2 <= 12 always inside this loop
        computeDi(di + 1, di + 2, WC, WD, xb, xt);
    }
    computeDi(12, 12, WA, WB, xb, xt);

    int cb = csplit * 32 + cc * 4;
#pragma unroll
    for (int k = 0; k < 7; k++)
#pragma unroll
        for (int q = 0; q < 4; q++)
            out[(k * 64 + cb + q) * HW + y] = acc[k][q];
}

// ---------------------------------------------------------------------------
extern "C" void kernel_launch(void* const* d_in, const int* in_sizes, int n_in,
                              void* d_out, int out_size, void* d_ws, size_t ws_size,
                              hipStream_t stream) {
    (void)in_sizes; (void)n_in; (void)out_size; (void)ws_size;
    const float* x  = (const float*)d_in[0];
    const float* xe = (const float*)d_in[1];
    const float* ye = (const float*)d_in[2];
    const float* lt = (const float*)d_in[3];
    float* out = (float*)d_out;
    char* ws = (char*)d_ws;

    // layout (98.3 MB total):
    u16*   xh     = (u16*)(ws + 0);            //  2,097,152 B (f16 [64][128][128])
    float* xeT    = (float*)(ws + 2097152u);   //  2,097,152
    float* yeT    = (float*)(ws + 4194304u);   //  2,097,152
    u16*   Wkt    = (u16*)(ws + 6291456u);     // 44,302,336 -> 50,593,792
    float* logits = (float*)(ws + 50593792u);  // 11,075,584 (dead after k_softmax)
    u32*   WsP    = (u32*)(ws + 50593792u);    // 47,710,208 -> 98,304,000 (overlays logits)
    // nx/ny/st overlay Wkt head: written by k_prep/k_norms, last read by
    // k_logits; Wkt is written later by k_softmax.
    float*  nx = (float*)(ws + 6291456u);             // 65,536
    float*  ny = (float*)(ws + 6291456u + 65536u);    // 65,536
    float2* st = (float2*)(ws + 6291456u + 131072u);  // 131,072

    k_prep<<<64, 256, 0, stream>>>(x, xe, ye, xh, xeT, yeT, nx, ny);
    k_norms<<<64, 256, 0, stream>>>(ny, lt, st);
    k_logits<<<dim3(13, 64), 1024, 0, stream>>>(xeT, yeT, nx, st, logits);
    k_softmax<<<512, 256, 0, stream>>>(logits, Wkt);
    k_wsum<<<dim3(91, 16), 256, 0, stream>>>(Wkt, WsP);
    k_agg<<<512, 512, 0, stream>>>(xh, WsP, out);
}

// Round 12
// 140.519 us; speedup vs baseline: 1.1774x; 1.1370x over previous
//
#include <hip/hip_runtime.h>
#include <hip/hip_bf16.h>
#include <hip/hip_fp16.h>

// N3 aggregation: C=64, E=32, H=W=128, K=7, PS=7 (PR=3), WS=13 (WR=6), O=169
#define HW 16384

using u16 = unsigned short;
using u32 = unsigned int;
typedef __attribute__((ext_vector_type(2))) float f32x2;

__device__ __forceinline__ u16 f2h(float f) {
    __half h = __float2half(f);
    return __builtin_bit_cast(u16, h);
}
// acc += a.x*b.x + a.y*b.y  (f16 pairs, f32 accumulate)
__device__ __forceinline__ void dot2acc(float& acc, u32 a, u32 b) {
    asm("v_dot2_f32_f16 %0, %1, %2, %0" : "+v"(acc) : "v"(a), "v"(b));
}
#define SELLO 0x05040100u
#define SELHI 0x07060302u

// ---------------------------------------------------------------------------
// K0: transposes + per-pixel HALF norms. grid 64 x 256. one thread per pixel.
//   nx2[0][y] = |xe[0:16](y)|^2, nx2[1][y] = |xe[16:32](y)|^2
// ---------------------------------------------------------------------------
__global__ __launch_bounds__(256) void k_prep(
        const float* __restrict__ x, const float* __restrict__ xe,
        const float* __restrict__ ye,
        u16* __restrict__ xh, float* __restrict__ xeT,
        float* __restrict__ yeT, float* __restrict__ nx2, float* __restrict__ ny) {
    int y = blockIdx.x * 256 + threadIdx.x;

#pragma unroll
    for (int c = 0; c < 64; c++)
        xh[c * HW + y] = f2h(x[c * HW + y]);

    float sx0 = 0.f, sx1 = 0.f, sy = 0.f;
#pragma unroll
    for (int e0 = 0; e0 < 32; e0 += 4) {
        float4 v = make_float4(xe[(e0 + 0) * HW + y], xe[(e0 + 1) * HW + y],
                               xe[(e0 + 2) * HW + y], xe[(e0 + 3) * HW + y]);
        *reinterpret_cast<float4*>(xeT + y * 32 + e0) = v;
        float s = v.x * v.x + v.y * v.y + v.z * v.z + v.w * v.w;
        if (e0 < 16) sx0 += s; else sx1 += s;
        float4 u = make_float4(ye[(e0 + 0) * HW + y], ye[(e0 + 1) * HW + y],
                               ye[(e0 + 2) * HW + y], ye[(e0 + 3) * HW + y]);
        *reinterpret_cast<float4*>(yeT + y * 32 + e0) = u;
        sy += u.x * u.x + u.y * u.y + u.z * u.z + u.w * u.w;
    }
    nx2[y] = sx0;
    nx2[HW + y] = sx1;
    ny[y] = sy;
}

// ---------------------------------------------------------------------------
// K0b: st[y] = (tinv, tinv*Sy), tinv = exp(-boxsum(lt)/49), Sy = boxsum(ny).
// ---------------------------------------------------------------------------
__global__ __launch_bounds__(256) void k_norms(
        const float* __restrict__ ny, const float* __restrict__ lt,
        float2* __restrict__ st) {
    int y = blockIdx.x * 256 + threadIdx.x;
    int py = y >> 7, px = y & 127;
    float s = 0.f, t = 0.f;
    for (int dy = -3; dy <= 3; dy++)
        for (int dx = -3; dx <= 3; dx++) {
            int yy = py + dy, xx = px + dx;
            if ((unsigned)yy < 128u && (unsigned)xx < 128u) {
                int p = yy * 128 + xx;
                s += ny[p];
                t += lt[p];
            }
        }
    float tinv = __expf(-t * (1.0f / 49.0f));
    st[y] = make_float2(tinv, tinv * s);
}

// ---------------------------------------------------------------------------
// K1 v3: E-SPLIT partial logits. grid (13 di, 64 tiles, 2 e-halves), 1024 thr.
// lg[h][o][y] = boxsum_z( nx_h(z+o) - 2 * ye_h(z) . xe_h(z+o) )   (raw, no fold)
// Arena 76KB -> 2 blocks/CU co-resident (v2 was 121KB -> 1/CU, phases fully
// latency-exposed). tinv/Sy fold moved to k_softmax.
// ---------------------------------------------------------------------------
__global__ __launch_bounds__(1024) void k_logits(
        const float* __restrict__ xeT, const float* __restrict__ yeT,
        const float* __restrict__ nx2, float* __restrict__ lg) {
#pragma clang fp contract(fast)
    __shared__ __align__(16) char arena[76032];
    float* s_xe = (float*)arena;              // 748 cells * 16 dw, chunk-swizzled
    float* s_nx = (float*)(arena + 47872);    // 748
    float* s_d2 = (float*)(arena + 50864);    // 13 * 484
    float* s_hs = (float*)arena;              // overlay after compute: 13*22*16

    int di = blockIdx.x;
    int tile = blockIdx.y;
    int h = blockIdx.z;                       // e-half
    int h0 = (tile >> 3) * 16, w0 = (tile & 7) * 16;
    int gr0 = h0 + di - 9, gc0 = w0 - 9;
    int tid = threadIdx.x;

    // stage xe half-halo: 748 cells x 4 float4-chunks, chunk-swizzled
    for (int idx = tid; idx < 748 * 4; idx += 1024) {
        int cell = idx >> 2, q = idx & 3;
        int r = cell / 34, c = cell - r * 34;
        int gy = gr0 + r, gx = gc0 + c;
        float4 v = make_float4(0.f, 0.f, 0.f, 0.f);
        if ((unsigned)gy < 128u && (unsigned)gx < 128u)
            v = *reinterpret_cast<const float4*>(
                    xeT + (size_t)(gy * 128 + gx) * 32 + h * 16 + q * 4);
        *reinterpret_cast<float4*>(s_xe + cell * 16 + ((q ^ (cell & 3)) << 2)) = v;
    }
    for (int idx = tid; idx < 748; idx += 1024) {
        int r = idx / 34, c = idx - r * 34;
        int gy = gr0 + r, gx = gc0 + c;
        float v = 0.f;
        if ((unsigned)gy < 128u && (unsigned)gx < 128u)
            v = nx2[h * HW + gy * 128 + gx];
        s_nx[idx] = v;
    }
    __syncthreads();

    if (tid < 484) {
        int zr = tid / 22, zc = tid - zr * 22;
        int gy = h0 - 3 + zr, gx = w0 - 3 + zc;
        bool zin = ((unsigned)gy < 128u) && ((unsigned)gx < 128u);
        f32x2 yv[8];
#pragma unroll
        for (int j = 0; j < 8; j++) yv[j] = (f32x2){0.f, 0.f};
        if (zin) {
            const float* yp = yeT + (size_t)(gy * 128 + gx) * 32 + h * 16;
#pragma unroll
            for (int j = 0; j < 4; j++) {
                float4 t = *reinterpret_cast<const float4*>(yp + j * 4);
                yv[2 * j] = (f32x2){t.x, t.y};
                yv[2 * j + 1] = (f32x2){t.z, t.w};
            }
        }
        int cell0 = zr * 34 + zc;
#pragma unroll
        for (int dj = 0; dj < 13; dj++) {
            int cell = cell0 + dj;
            const float* bp = s_xe + cell * 16;
            int sw = cell & 3;
            f32x2 a0 = {0.f, 0.f}, a1 = {0.f, 0.f};
#pragma unroll
            for (int q = 0; q < 4; q++) {
                float4 xv = *reinterpret_cast<const float4*>(bp + ((q ^ sw) << 2));
                a0 += ((f32x2){xv.x, xv.y}) * yv[2 * q];
                a1 += ((f32x2){xv.z, xv.w}) * yv[2 * q + 1];
            }
            float cr = a0.x + a0.y + a1.x + a1.y;
            float d2v = fmaf(-2.f, cr, s_nx[cell]);
            s_d2[dj * 484 + tid] = zin ? d2v : 0.f;
        }
    }
    __syncthreads();

    // horizontal 7-tap: 13 x 22 x 16 -> s_hs (overlays s_xe)
    for (int idx = tid; idx < 4576; idx += 1024) {
        int dj = idx / 352, rem = idx - dj * 352;
        int r = rem >> 4, c = rem & 15;
        const float* p = s_d2 + dj * 484 + r * 22 + c;
        float s = p[0] + p[1] + p[2] + p[3] + p[4] + p[5] + p[6];
        s_hs[(dj * 22 + r) * 16 + c] = s;
    }
    __syncthreads();

    // vertical 7-tap + store raw partial boxsum
    for (int idx = tid; idx < 3328; idx += 1024) {
        int dj = idx >> 8, rem = idx & 255;
        int i = rem >> 4, jj = rem & 15;
        const float* p = s_hs + (dj * 22 + i) * 16 + jj;
        float s = p[0] + p[16] + p[32] + p[48] + p[64] + p[80] + p[96];
        int y = (h0 + i) * 128 + (w0 + jj);
        lg[((size_t)h * 169 + di * 13 + dj) * HW + y] = s;
    }
}

// ---------------------------------------------------------------------------
// K2: K=7 rounds of exclusion softmax over O=169. grid 512 x 256.
// Now sums the two e-half partial boxsums and applies the -(tinv*bs + tinv*Sy)
// fold (st[y]) during staging.
// ---------------------------------------------------------------------------
__global__ __launch_bounds__(256) void k_softmax(
        const float* __restrict__ lg, const float2* __restrict__ st,
        u16* __restrict__ Wkt) {
    __shared__ float s_lg[169 * 34];
    int tid = threadIdx.x;
    int y0 = blockIdx.x * 32;
    for (int idx = tid; idx < 169 * 32; idx += 256) {
        int o = idx >> 5, p = idx & 31;
        s_lg[o * 34 + p] = lg[(size_t)o * HW + y0 + p]
                         + lg[(size_t)(169 + o) * HW + y0 + p];
    }
    __syncthreads();
    int pix = tid >> 3, t = tid & 7;
    int y = y0 + pix;
    float2 ab = st[y];
    float l[22];
#pragma unroll
    for (int j = 0; j < 22; j++) {
        int o = t + 8 * j;
        l[j] = (o < 169) ? -fmaf(ab.x, s_lg[o * 34 + pix], ab.y) : -3e38f;
    }
    u32 wp0[22], wp1[22], wp2[22], wp3[22];
#pragma unroll
    for (int j = 0; j < 22; j++) { wp0[j] = 0u; wp1[j] = 0u; wp2[j] = 0u; wp3[j] = 0u; }

    float e[22];
#pragma unroll
    for (int k = 0; k < 7; k++) {
        float m = -3e38f;
#pragma unroll
        for (int j = 0; j < 22; j++) m = fmaxf(m, l[j]);
        m = fmaxf(m, __shfl_xor(m, 1));
        m = fmaxf(m, __shfl_xor(m, 2));
        m = fmaxf(m, __shfl_xor(m, 4));
        float s = 0.f;
#pragma unroll
        for (int j = 0; j < 22; j++) { e[j] = __expf(l[j] - m); s += e[j]; }
        s += __shfl_xor(s, 1);
        s += __shfl_xor(s, 2);
        s += __shfl_xor(s, 4);
        float rs = 1.0f / s;
#pragma unroll
        for (int j = 0; j < 22; j++) {
            float w = e[j] * rs;
            u32 hh = (u32)f2h(w);
            if (k == 0) wp0[j] |= hh;
            else if (k == 1) wp0[j] |= hh << 16;
            else if (k == 2) wp1[j] |= hh;
            else if (k == 3) wp1[j] |= hh << 16;
            else if (k == 4) wp2[j] |= hh;
            else if (k == 5) wp2[j] |= hh << 16;
            else wp3[j] |= hh;
            if (k < 6) l[j] += __logf(fmaxf(1.0f - w, 1e-6f));
        }
    }
#pragma unroll
    for (int j = 0; j < 22; j++) {
        int o = t + 8 * j;
        if (o < 169)
            *reinterpret_cast<uint4*>(Wkt + ((size_t)o * HW + y) * 8) =
                make_uint4(wp0[j], wp1[j], wp2[j], wp3[j]);
    }
}

// ---------------------------------------------------------------------------
// K2b v2: 7x7 boxsum of Wkt(f16) -> PAIR-PACKED WsP[o2][y][8 u32],
// u32[k] = (f16 w(di,2djp,k) , f16 w(di,2djp+1,k)); slot 7 = 0. (unchanged)
// ---------------------------------------------------------------------------
__global__ __launch_bounds__(256) void k_wsum(
        const u16* __restrict__ Wkt, u32* __restrict__ WsP) {
    __shared__ u16 s_w[38 * 39 * 8];   // [row][col pad39][k8]
    __shared__ u16 s_v[32 * 38 * 8];   // [outrow][col][k8] f16 vertical sums
    int o2 = blockIdx.x;
    int di = o2 / 7, djp = o2 - di * 7;
    int oA = di * 13 + 2 * djp;
    bool hasB = (djp < 6);
    int tile = blockIdx.y;
    int h0 = (tile >> 2) * 32, w0 = (tile & 3) * 32;
    int tid = threadIdx.x;

    auto stage = [&](int o) {
        const u16* src = Wkt + (size_t)o * (HW * 8);
        for (int idx = tid; idx < 38 * 38; idx += 256) {
            int r = idx / 38, c = idx - r * 38;
            int gy = h0 - 3 + r, gx = w0 - 3 + c;
            uint4 v = make_uint4(0u, 0u, 0u, 0u);
            if ((unsigned)gy < 128u && (unsigned)gx < 128u)
                v = *reinterpret_cast<const uint4*>(src + (gy * 128 + gx) * 8);
            *reinterpret_cast<uint4*>(s_w + (r * 39 + c) * 8) = v;
        }
    };
    auto vert = [&]() {
        for (int u = tid; u < 1216; u += 256) {   // 32 out-rows x 38 cols
            int r = u / 38, c = u - r * 38;
            __half2 s0 = __builtin_bit_cast(__half2, 0u);
            __half2 s1 = s0, s2 = s0, s3 = s0;
#pragma unroll
            for (int d = 0; d < 7; d++) {
                uint4 q = *reinterpret_cast<const uint4*>(s_w + ((r + d) * 39 + c) * 8);
                s0 = __hadd2(s0, __builtin_bit_cast(__half2, q.x));
                s1 = __hadd2(s1, __builtin_bit_cast(__half2, q.y));
                s2 = __hadd2(s2, __builtin_bit_cast(__half2, q.z));
                s3 = __hadd2(s3, __builtin_bit_cast(__half2, q.w));
            }
            *reinterpret_cast<uint4*>(s_v + (r * 38 + c) * 8) = make_uint4(
                __builtin_bit_cast(u32, s0), __builtin_bit_cast(u32, s1),
                __builtin_bit_cast(u32, s2), __builtin_bit_cast(u32, s3));
        }
    };
    auto horiz = [&](uint4 (&rr)[4]) {
#pragma unroll
        for (int i = 0; i < 4; i++) {              // 32 rows x 32 out-cols
            int u = tid + i * 256;
            int r = u >> 5, cx = u & 31;
            __half2 s0 = __builtin_bit_cast(__half2, 0u);
            __half2 s1 = s0, s2 = s0, s3 = s0;
#pragma unroll
            for (int d = 0; d < 7; d++) {
                uint4 q = *reinterpret_cast<const uint4*>(s_v + (r * 38 + cx + d) * 8);
                s0 = __hadd2(s0, __builtin_bit_cast(__half2, q.x));
                s1 = __hadd2(s1, __builtin_bit_cast(__half2, q.y));
                s2 = __hadd2(s2, __builtin_bit_cast(__half2, q.z));
                s3 = __hadd2(s3, __builtin_bit_cast(__half2, q.w));
            }
            rr[i] = make_uint4(
                __builtin_bit_cast(u32, s0), __builtin_bit_cast(u32, s1),
                __builtin_bit_cast(u32, s2), __builtin_bit_cast(u32, s3));
        }
    };

    uint4 rA[4], rB[4];
#pragma unroll
    for (int i = 0; i < 4; i++) rB[i] = make_uint4(0u, 0u, 0u, 0u);

    stage(oA);
    __syncthreads();
    vert();
    __syncthreads();
    horiz(rA);
    if (hasB) {
        __syncthreads();           // rA-horiz reads done; safe to overwrite s_w
        stage(oA + 1);
        __syncthreads();
        vert();
        __syncthreads();
        horiz(rB);
    }

#pragma unroll
    for (int i = 0; i < 4; i++) {
        int u = tid + i * 256;
        int r = u >> 5, cx = u & 31;
        int y = (h0 + r) * 128 + (w0 + cx);
        u32* dst = WsP + ((size_t)o2 * HW + y) * 8;
        uint4 lo = make_uint4(
            __builtin_amdgcn_perm(rB[i].x, rA[i].x, SELLO),
            __builtin_amdgcn_perm(rB[i].x, rA[i].x, SELHI),
            __builtin_amdgcn_perm(rB[i].y, rA[i].y, SELLO),
            __builtin_amdgcn_perm(rB[i].y, rA[i].y, SELHI));
        uint4 hi = make_uint4(
            __builtin_amdgcn_perm(rB[i].z, rA[i].z, SELLO),
            __builtin_amdgcn_perm(rB[i].z, rA[i].z, SELHI),
            __builtin_amdgcn_perm(rB[i].w, rA[i].w, SELLO),
            0u);
        *reinterpret_cast<uint4*>(dst) = lo;
        *reinterpret_cast<uint4*>(dst + 4) = hi;
    }
}

// ---------------------------------------------------------------------------
// K3 = v7 (best measured: 44.2us). Whole-C blocks (W fetched once per pixel,
// L1-broadcast across the 8 cc waves) + pair-packed WsP + di ping-pong W
// prefetch. grid 256 tiles (4x16 pix); 512 thr = 64 pix x 8 cc (8ch each).
// s_x [64ch][16r][32c] f16 = 64KB.
// ---------------------------------------------------------------------------
__global__ __launch_bounds__(512, 2) void k_agg(
        const u16* __restrict__ xh, const u32* __restrict__ WsP,
        float* __restrict__ out) {
    __shared__ u16 s_x[64 * 16 * 32];   // [ch][r][c] f16, 64KB
    int tb = blockIdx.x;
    int h0 = (tb >> 3) * 4, w0 = (tb & 7) * 16;
    int tid = threadIdx.x;

#pragma unroll
    for (int i = 0; i < 8; i++) {
        int it = tid + i * 512;
        int ch = it >> 6;
        int r = (it >> 2) & 15;
        int c0 = (it & 3) * 8;
        int gy = h0 - 6 + r, gx0 = w0 - 6 + c0;
        uint4 v = make_uint4(0u, 0u, 0u, 0u);
        if ((unsigned)gy < 128u) {
            const u16* src = xh + (size_t)ch * HW + gy * 128;
            if (gx0 >= 0 && gx0 <= 120) {
                v = *reinterpret_cast<const uint4*>(src + gx0);
            } else {
                auto pk = [&](int gx) -> u32 {
                    u32 lo = ((unsigned)gx < 128u) ? (u32)src[gx] : 0u;
                    u32 hi = ((unsigned)(gx + 1) < 128u) ? (u32)src[gx + 1] : 0u;
                    return lo | (hi << 16);
                };
                v = make_uint4(pk(gx0), pk(gx0 + 2), pk(gx0 + 4), pk(gx0 + 6));
            }
        }
        *reinterpret_cast<uint4*>(s_x + (ch * 16 + r) * 32 + c0) = v;
    }
    __syncthreads();

    int cc = tid >> 6, pix = tid & 63;
    int pr = pix >> 4, pc = pix & 15;
    int y = (h0 + pr) * 128 + (w0 + pc);
    const u32* wsrc = WsP + (size_t)y * 8;
    const u32* s_x32 = reinterpret_cast<const u32*>(s_x);
    u32 sh = (u32)(pc & 1) * 16;
    int base0 = cc * 8 * 256 + (pc >> 1);   // + q*256 + (pr+di)*16

    float acc[7][8];
#pragma unroll
    for (int k = 0; k < 7; k++)
#pragma unroll
        for (int q = 0; q < 8; q++) acc[k][q] = 0.f;

    auto loadW = [&](int di, uint4 (&A)[7], uint4 (&B)[7]) {
        const u32* wdi = wsrc + (size_t)(di * 7) * (HW * 8);
#pragma unroll
        for (int djp = 0; djp < 7; djp++) {
            const u32* wp = wdi + (size_t)djp * (HW * 8);
            A[djp] = *reinterpret_cast<const uint4*>(wp);
            B[djp] = *reinterpret_cast<const uint4*>(wp + 4);
        }
    };
    auto compute = [&](int di, const uint4 (&A)[7], const uint4 (&B)[7]) {
        int rowoff = (pr + di) * 16;
#pragma unroll
        for (int q = 0; q < 8; q++) {
            const u32* p = s_x32 + base0 + q * 256 + rowoff;
            u32 f0 = p[0], f1 = p[1], f2 = p[2], f3 = p[3];
            u32 f4 = p[4], f5 = p[5], f6 = p[6], f7 = p[7];
            u32 x2;
            x2 = __builtin_amdgcn_alignbit(f1, f0, sh);
            dot2acc(acc[0][q], A[0].x, x2); dot2acc(acc[1][q], A[0].y, x2);
            dot2acc(acc[2][q], A[0].z, x2); dot2acc(acc[3][q], A[0].w, x2);
            dot2acc(acc[4][q], B[0].x, x2); dot2acc(acc[5][q], B[0].y, x2);
            dot2acc(acc[6][q], B[0].z, x2);
            x2 = __builtin_amdgcn_alignbit(f2, f1, sh);
            dot2acc(acc[0][q], A[1].x, x2); dot2acc(acc[1][q], A[1].y, x2);
            dot2acc(acc[2][q], A[1].z, x2); dot2acc(acc[3][q], A[1].w, x2);
            dot2acc(acc[4][q], B[1].x, x2); dot2acc(acc[5][q], B[1].y, x2);
            dot2acc(acc[6][q], B[1].z, x2);
            x2 = __builtin_amdgcn_alignbit(f3, f2, sh);
            dot2acc(acc[0][q], A[2].x, x2); dot2acc(acc[1][q], A[2].y, x2);
            dot2acc(acc[2][q], A[2].z, x2); dot2acc(acc[3][q], A[2].w, x2);
            dot2acc(acc[4][q], B[2].x, x2); dot2acc(acc[5][q], B[2].y, x2);
            dot2acc(acc[6][q], B[2].z, x2);
            x2 = __builtin_amdgcn_alignbit(f4, f3, sh);
            dot2acc(acc[0][q], A[3].x, x2); dot2acc(acc[1][q], A[3].y, x2);
            dot2acc(acc[2][q], A[3].z, x2); dot2acc(acc[3][q], A[3].w, x2);
            dot2acc(acc[4][q], B[3].x, x2); dot2acc(acc[5][q], B[3].y, x2);
            dot2acc(acc[6][q], B[3].z, x2);
            x2 = __builtin_amdgcn_alignbit(f5, f4, sh);
            dot2acc(acc[0][q], A[4].x, x2); dot2acc(acc[1][q], A[4].y, x2);
            dot2acc(acc[2][q], A[4].z, x2); dot2acc(acc[3][q], A[4].w, x2);
            dot2acc(acc[4][q], B[4].x, x2); dot2acc(acc[5][q], B[4].y, x2);
            dot2acc(acc[6][q], B[4].z, x2);
            x2 = __builtin_amdgcn_alignbit(f6, f5, sh);
            dot2acc(acc[0][q], A[5].x, x2); dot2acc(acc[1][q], A[5].y, x2);
            dot2acc(acc[2][q], A[5].z, x2); dot2acc(acc[3][q], A[5].w, x2);
            dot2acc(acc[4][q], B[5].x, x2); dot2acc(acc[5][q], B[5].y, x2);
            dot2acc(acc[6][q], B[5].z, x2);
            x2 = __builtin_amdgcn_alignbit(f7, f6, sh);
            dot2acc(acc[0][q], A[6].x, x2); dot2acc(acc[1][q], A[6].y, x2);
            dot2acc(acc[2][q], A[6].z, x2); dot2acc(acc[3][q], A[6].w, x2);
            dot2acc(acc[4][q], B[6].x, x2); dot2acc(acc[5][q], B[6].y, x2);
            dot2acc(acc[6][q], B[6].z, x2);
        }
    };

    uint4 WA[7], WB[7], WC[7], WD[7];
    loadW(0, WA, WB);
#pragma unroll 1
    for (int di = 0; di < 12; di += 2) {
        loadW(di + 1, WC, WD);     // prefetch next di while computing current
        compute(di, WA, WB);
        loadW(di + 2, WA, WB);     // di+2 <= 12 always inside this loop
        compute(di + 1, WC, WD);
    }
    compute(12, WA, WB);

#pragma unroll
    for (int k = 0; k < 7; k++)
#pragma unroll
        for (int q = 0; q < 8; q++)
            out[(k * 64 + cc * 8 + q) * HW + y] = acc[k][q];
}

// ---------------------------------------------------------------------------
extern "C" void kernel_launch(void* const* d_in, const int* in_sizes, int n_in,
                              void* d_out, int out_size, void* d_ws, size_t ws_size,
                              hipStream_t stream) {
    (void)in_sizes; (void)n_in; (void)out_size; (void)ws_size;
    const float* x  = (const float*)d_in[0];
    const float* xe = (const float*)d_in[1];
    const float* ye = (const float*)d_in[2];
    const float* lt = (const float*)d_in[3];
    float* out = (float*)d_out;
    char* ws = (char*)d_ws;

    // layout (~121 MB; d_ws is ~256MB per harness poison size). All disjoint.
    u16*    xh  = (u16*)(ws + 0);              //  2,097,152 B (f16 [64][128][128])
    float*  xeT = (float*)(ws + 2097152u);     //  2,097,152
    float*  yeT = (float*)(ws + 4194304u);     //  2,097,152
    u16*    Wkt = (u16*)(ws + 6291456u);       // 44,302,336 -> 50,593,792
    float*  lg  = (float*)(ws + 50593792u);    // 2*169*HW*4 = 22,151,168 -> 72,744,960
    u32*    WsP = (u32*)(ws + 72744960u);      // 47,710,208 -> 120,455,168
    float*  nx2 = (float*)(ws + 120455168u);   // 131,072
    float*  ny  = (float*)(ws + 120586240u);   //  65,536
    float2* st  = (float2*)(ws + 120651776u);  // 131,072 -> ends 120,782,848

    k_prep<<<64, 256, 0, stream>>>(x, xe, ye, xh, xeT, yeT, nx2, ny);
    k_norms<<<64, 256, 0, stream>>>(ny, lt, st);
    k_logits<<<dim3(13, 64, 2), 1024, 0, stream>>>(xeT, yeT, nx2, lg);
    k_softmax<<<512, 256, 0, stream>>>(lg, st, Wkt);
    k_wsum<<<dim3(91, 16), 256, 0, stream>>>(Wkt, WsP);
    k_agg<<<256, 512, 0, stream>>>(xh, WsP, out);
}

// Round 14
// 135.449 us; speedup vs baseline: 1.2215x; 1.0374x over previous
//
#include <hip/hip_runtime.h>
#include <hip/hip_bf16.h>
#include <hip/hip_fp16.h>

// N3 aggregation: C=64, E=32, H=W=128, K=7, PS=7 (PR=3), WS=13 (WR=6), O=169
#define HW 16384

using u16 = unsigned short;
using u32 = unsigned int;
typedef __attribute__((ext_vector_type(2))) float f32x2;

__device__ __forceinline__ u16 f2h(float f) {
    __half h = __float2half(f);
    return __builtin_bit_cast(u16, h);
}
// acc += a.x*b.x + a.y*b.y  (f16 pairs, f32 accumulate)
__device__ __forceinline__ void dot2acc(float& acc, u32 a, u32 b) {
    asm("v_dot2_f32_f16 %0, %1, %2, %0" : "+v"(acc) : "v"(a), "v"(b));
}
#define SELLO 0x05040100u
#define SELHI 0x07060302u

// ---------------------------------------------------------------------------
// K0: transposes + per-pixel HALF norms. grid 64 x 256. one thread per pixel.
// xe/ye stay f32 (logit path is precision-critical: f16 embeddings measured
// absmax 64 in round 13 — candidate ties within the f16 noise get re-ranked).
// ---------------------------------------------------------------------------
__global__ __launch_bounds__(256) void k_prep(
        const float* __restrict__ x, const float* __restrict__ xe,
        const float* __restrict__ ye,
        u16* __restrict__ xh, float* __restrict__ xeT,
        float* __restrict__ yeT, float* __restrict__ nx2, float* __restrict__ ny) {
    int y = blockIdx.x * 256 + threadIdx.x;

#pragma unroll
    for (int c = 0; c < 64; c++)
        xh[c * HW + y] = f2h(x[c * HW + y]);

    float sx0 = 0.f, sx1 = 0.f, sy = 0.f;
#pragma unroll
    for (int e0 = 0; e0 < 32; e0 += 4) {
        float4 v = make_float4(xe[(e0 + 0) * HW + y], xe[(e0 + 1) * HW + y],
                               xe[(e0 + 2) * HW + y], xe[(e0 + 3) * HW + y]);
        *reinterpret_cast<float4*>(xeT + y * 32 + e0) = v;
        float s = v.x * v.x + v.y * v.y + v.z * v.z + v.w * v.w;
        if (e0 < 16) sx0 += s; else sx1 += s;
        float4 u = make_float4(ye[(e0 + 0) * HW + y], ye[(e0 + 1) * HW + y],
                               ye[(e0 + 2) * HW + y], ye[(e0 + 3) * HW + y]);
        *reinterpret_cast<float4*>(yeT + y * 32 + e0) = u;
        sy += u.x * u.x + u.y * u.y + u.z * u.z + u.w * u.w;
    }
    nx2[y] = sx0;
    nx2[HW + y] = sx1;
    ny[y] = sy;
}

// ---------------------------------------------------------------------------
// K0b: st[y] = (tinv, tinv*Sy), tinv = exp(-boxsum(lt)/49), Sy = boxsum(ny).
// ---------------------------------------------------------------------------
__global__ __launch_bounds__(256) void k_norms(
        const float* __restrict__ ny, const float* __restrict__ lt,
        float2* __restrict__ st) {
    int y = blockIdx.x * 256 + threadIdx.x;
    int py = y >> 7, px = y & 127;
    float s = 0.f, t = 0.f;
    for (int dy = -3; dy <= 3; dy++)
        for (int dx = -3; dx <= 3; dx++) {
            int yy = py + dy, xx = px + dx;
            if ((unsigned)yy < 128u && (unsigned)xx < 128u) {
                int p = yy * 128 + xx;
                s += ny[p];
                t += lt[p];
            }
        }
    float tinv = __expf(-t * (1.0f / 49.0f));
    st[y] = make_float2(tinv, tinv * s);
}

// ---------------------------------------------------------------------------
// K1 v5: E-split partial logits, f32 embeddings (precision-critical) +
// VECTORIZED 7-tap sums (sliding-window b128 hsum, float4 vsum + f4 store).
// grid (13 di, 64 tiles, 2 e-halves), 1024 thr. Arena 78.3KB -> 2 blocks/CU.
// lg[h][o][y] = boxsum_z( nx_h(z+o) - 2 * ye_h(z) . xe_h(z+o) )  (raw)
// ---------------------------------------------------------------------------
__global__ __launch_bounds__(1024) void k_logits(
        const float* __restrict__ xeT, const float* __restrict__ yeT,
        const float* __restrict__ nx2, float* __restrict__ lg) {
#pragma clang fp contract(fast)
    __shared__ __align__(16) char arena[78320];
    float* s_xe = (float*)arena;              // 748 cells * 16 dw, chunk-swizzled
    float* s_nx = (float*)(arena + 47872);    // 748 f32
    float* s_d2 = (float*)(arena + 50864);    // [13][22][24] f32
    float* s_hs = (float*)arena;              // overlay: [13][22][16] f32

    int di = blockIdx.x;
    int tile = blockIdx.y;
    int h = blockIdx.z;                       // e-half
    int h0 = (tile >> 3) * 16, w0 = (tile & 7) * 16;
    int gr0 = h0 + di - 9, gc0 = w0 - 9;
    int tid = threadIdx.x;

    // stage xe half-halo: 748 cells x 4 float4-chunks, chunk-swizzled
    for (int idx = tid; idx < 748 * 4; idx += 1024) {
        int cell = idx >> 2, q = idx & 3;
        int r = cell / 34, c = cell - r * 34;
        int gy = gr0 + r, gx = gc0 + c;
        float4 v = make_float4(0.f, 0.f, 0.f, 0.f);
        if ((unsigned)gy < 128u && (unsigned)gx < 128u)
            v = *reinterpret_cast<const float4*>(
                    xeT + (size_t)(gy * 128 + gx) * 32 + h * 16 + q * 4);
        *reinterpret_cast<float4*>(s_xe + cell * 16 + ((q ^ (cell & 3)) << 2)) = v;
    }
    for (int idx = tid; idx < 748; idx += 1024) {
        int r = idx / 34, c = idx - r * 34;
        int gy = gr0 + r, gx = gc0 + c;
        float v = 0.f;
        if ((unsigned)gy < 128u && (unsigned)gx < 128u)
            v = nx2[h * HW + gy * 128 + gx];
        s_nx[idx] = v;
    }
    __syncthreads();

    if (tid < 484) {
        int zr = tid / 22, zc = tid - zr * 22;
        int gy = h0 - 3 + zr, gx = w0 - 3 + zc;
        bool zin = ((unsigned)gy < 128u) && ((unsigned)gx < 128u);
        f32x2 yv[8];
#pragma unroll
        for (int j = 0; j < 8; j++) yv[j] = (f32x2){0.f, 0.f};
        if (zin) {
            const float* yp = yeT + (size_t)(gy * 128 + gx) * 32 + h * 16;
#pragma unroll
            for (int j = 0; j < 4; j++) {
                float4 t = *reinterpret_cast<const float4*>(yp + j * 4);
                yv[2 * j] = (f32x2){t.x, t.y};
                yv[2 * j + 1] = (f32x2){t.z, t.w};
            }
        }
        int cell0 = zr * 34 + zc;
#pragma unroll
        for (int dj = 0; dj < 13; dj++) {
            int cell = cell0 + dj;
            const float* bp = s_xe + cell * 16;
            int sw = cell & 3;
            f32x2 a0 = {0.f, 0.f}, a1 = {0.f, 0.f};
#pragma unroll
            for (int q = 0; q < 4; q++) {
                float4 xv = *reinterpret_cast<const float4*>(bp + ((q ^ sw) << 2));
                a0 += ((f32x2){xv.x, xv.y}) * yv[2 * q];
                a1 += ((f32x2){xv.z, xv.w}) * yv[2 * q + 1];
            }
            float cr = a0.x + a0.y + a1.x + a1.y;
            float d2v = fmaf(-2.f, cr, s_nx[cell]);
            s_d2[dj * 528 + zr * 24 + zc] = zin ? d2v : 0.f;
        }
    }
    __syncthreads();

    // horizontal 7-tap, 4 outputs/thread via sliding window: 13*22*4 units
    for (int idx = tid; idx < 1144; idx += 1024) {
        int dj = idx / 88, rem = idx - dj * 88;
        int r = rem >> 2, c4 = (rem & 3) * 4;
        const float* p = s_d2 + dj * 528 + r * 24 + c4;
        float4 pa = *reinterpret_cast<const float4*>(p);
        float4 pb = *reinterpret_cast<const float4*>(p + 4);
        float4 pc = *reinterpret_cast<const float4*>(p + 8);
        float h0s = pa.x + pa.y + pa.z + pa.w + pb.x + pb.y + pb.z;
        float h1s = h0s - pa.x + pb.w;
        float h2s = h1s - pa.y + pc.x;
        float h3s = h2s - pa.z + pc.y;
        *reinterpret_cast<float4*>(s_hs + (dj * 22 + r) * 16 + c4) =
            make_float4(h0s, h1s, h2s, h3s);
    }
    __syncthreads();

    // vertical 7-tap + store raw partial boxsum: 13*16*4 units, float4 each
    for (int idx = tid; idx < 832; idx += 1024) {
        int dj = idx >> 6, rem = idx & 63;
        int i = rem >> 2, j4 = (rem & 3) * 4;
        const float* p = s_hs + (dj * 22 + i) * 16 + j4;
        float4 s = *reinterpret_cast<const float4*>(p);
#pragma unroll
        for (int d = 1; d < 7; d++) {
            float4 t = *reinterpret_cast<const float4*>(p + d * 16);
            s.x += t.x; s.y += t.y; s.z += t.z; s.w += t.w;
        }
        int y = (h0 + i) * 128 + (w0 + j4);
        *reinterpret_cast<float4*>(
            lg + ((size_t)h * 169 + di * 13 + dj) * HW + y) = s;
    }
}

// ---------------------------------------------------------------------------
// K2: K=7 rounds of exclusion softmax over O=169. grid 512 x 256.
// Sums the two e-half partials and applies -(tinv*bs + tinv*Sy) during stage.
// ---------------------------------------------------------------------------
__global__ __launch_bounds__(256) void k_softmax(
        const float* __restrict__ lg, const float2* __restrict__ st,
        u16* __restrict__ Wkt) {
    __shared__ float s_lg[169 * 34];
    int tid = threadIdx.x;
    int y0 = blockIdx.x * 32;
    for (int idx = tid; idx < 169 * 32; idx += 256) {
        int o = idx >> 5, p = idx & 31;
        s_lg[o * 34 + p] = lg[(size_t)o * HW + y0 + p]
                         + lg[(size_t)(169 + o) * HW + y0 + p];
    }
    __syncthreads();
    int pix = tid >> 3, t = tid & 7;
    int y = y0 + pix;
    float2 ab = st[y];
    float l[22];
#pragma unroll
    for (int j = 0; j < 22; j++) {
        int o = t + 8 * j;
        l[j] = (o < 169) ? -fmaf(ab.x, s_lg[o * 34 + pix], ab.y) : -3e38f;
    }
    u32 wp0[22], wp1[22], wp2[22], wp3[22];
#pragma unroll
    for (int j = 0; j < 22; j++) { wp0[j] = 0u; wp1[j] = 0u; wp2[j] = 0u; wp3[j] = 0u; }

    float e[22];
#pragma unroll
    for (int k = 0; k < 7; k++) {
        float m = -3e38f;
#pragma unroll
        for (int j = 0; j < 22; j++) m = fmaxf(m, l[j]);
        m = fmaxf(m, __shfl_xor(m, 1));
        m = fmaxf(m, __shfl_xor(m, 2));
        m = fmaxf(m, __shfl_xor(m, 4));
        float s = 0.f;
#pragma unroll
        for (int j = 0; j < 22; j++) { e[j] = __expf(l[j] - m); s += e[j]; }
        s += __shfl_xor(s, 1);
        s += __shfl_xor(s, 2);
        s += __shfl_xor(s, 4);
        float rs = 1.0f / s;
#pragma unroll
        for (int j = 0; j < 22; j++) {
            float w = e[j] * rs;
            u32 hh = (u32)f2h(w);
            if (k == 0) wp0[j] |= hh;
            else if (k == 1) wp0[j] |= hh << 16;
            else if (k == 2) wp1[j] |= hh;
            else if (k == 3) wp1[j] |= hh << 16;
            else if (k == 4) wp2[j] |= hh;
            else if (k == 5) wp2[j] |= hh << 16;
            else wp3[j] |= hh;
            if (k < 6) l[j] += __logf(fmaxf(1.0f - w, 1e-6f));
        }
    }
#pragma unroll
    for (int j = 0; j < 22; j++) {
        int o = t + 8 * j;
        if (o < 169)
            *reinterpret_cast<uint4*>(Wkt + ((size_t)o * HW + y) * 8) =
                make_uint4(wp0[j], wp1[j], wp2[j], wp3[j]);
    }
}

// ---------------------------------------------------------------------------
// K2b v2: 7x7 boxsum of Wkt(f16) -> PAIR-PACKED WsP[o2][y][8 u32]. (unchanged)
// ---------------------------------------------------------------------------
__global__ __launch_bounds__(256) void k_wsum(
        const u16* __restrict__ Wkt, u32* __restrict__ WsP) {
    __shared__ u16 s_w[38 * 39 * 8];   // [row][col pad39][k8]
    __shared__ u16 s_v[32 * 38 * 8];   // [outrow][col][k8] f16 vertical sums
    int o2 = blockIdx.x;
    int di = o2 / 7, djp = o2 - di * 7;
    int oA = di * 13 + 2 * djp;
    bool hasB = (djp < 6);
    int tile = blockIdx.y;
    int h0 = (tile >> 2) * 32, w0 = (tile & 3) * 32;
    int tid = threadIdx.x;

    auto stage = [&](int o) {
        const u16* src = Wkt + (size_t)o * (HW * 8);
        for (int idx = tid; idx < 38 * 38; idx += 256) {
            int r = idx / 38, c = idx - r * 38;
            int gy = h0 - 3 + r, gx = w0 - 3 + c;
            uint4 v = make_uint4(0u, 0u, 0u, 0u);
            if ((unsigned)gy < 128u && (unsigned)gx < 128u)
                v = *reinterpret_cast<const uint4*>(src + (gy * 128 + gx) * 8);
            *reinterpret_cast<uint4*>(s_w + (r * 39 + c) * 8) = v;
        }
    };
    auto vert = [&]() {
        for (int u = tid; u < 1216; u += 256) {   // 32 out-rows x 38 cols
            int r = u / 38, c = u - r * 38;
            __half2 s0 = __builtin_bit_cast(__half2, 0u);
            __half2 s1 = s0, s2 = s0, s3 = s0;
#pragma unroll
            for (int d = 0; d < 7; d++) {
                uint4 q = *reinterpret_cast<const uint4*>(s_w + ((r + d) * 39 + c) * 8);
                s0 = __hadd2(s0, __builtin_bit_cast(__half2, q.x));
                s1 = __hadd2(s1, __builtin_bit_cast(__half2, q.y));
                s2 = __hadd2(s2, __builtin_bit_cast(__half2, q.z));
                s3 = __hadd2(s3, __builtin_bit_cast(__half2, q.w));
            }
            *reinterpret_cast<uint4*>(s_v + (r * 38 + c) * 8) = make_uint4(
                __builtin_bit_cast(u32, s0), __builtin_bit_cast(u32, s1),
                __builtin_bit_cast(u32, s2), __builtin_bit_cast(u32, s3));
        }
    };
    auto horiz = [&](uint4 (&rr)[4]) {
#pragma unroll
        for (int i = 0; i < 4; i++) {              // 32 rows x 32 out-cols
            int u = tid + i * 256;
            int r = u >> 5, cx = u & 31;
            __half2 s0 = __builtin_bit_cast(__half2, 0u);
            __half2 s1 = s0, s2 = s0, s3 = s0;
#pragma unroll
            for (int d = 0; d < 7; d++) {
                uint4 q = *reinterpret_cast<const uint4*>(s_v + (r * 38 + cx + d) * 8);
                s0 = __hadd2(s0, __builtin_bit_cast(__half2, q.x));
                s1 = __hadd2(s1, __builtin_bit_cast(__half2, q.y));
                s2 = __hadd2(s2, __builtin_bit_cast(__half2, q.z));
                s3 = __hadd2(s3, __builtin_bit_cast(__half2, q.w));
            }
            rr[i] = make_uint4(
                __builtin_bit_cast(u32, s0), __builtin_bit_cast(u32, s1),
                __builtin_bit_cast(u32, s2), __builtin_bit_cast(u32, s3));
        }
    };

    uint4 rA[4], rB[4];
#pragma unroll
    for (int i = 0; i < 4; i++) rB[i] = make_uint4(0u, 0u, 0u, 0u);

    stage(oA);
    __syncthreads();
    vert();
    __syncthreads();
    horiz(rA);
    if (hasB) {
        __syncthreads();           // rA-horiz reads done; safe to overwrite s_w
        stage(oA + 1);
        __syncthreads();
        vert();
        __syncthreads();
        horiz(rB);
    }

#pragma unroll
    for (int i = 0; i < 4; i++) {
        int u = tid + i * 256;
        int r = u >> 5, cx = u & 31;
        int y = (h0 + r) * 128 + (w0 + cx);
        u32* dst = WsP + ((size_t)o2 * HW + y) * 8;
        uint4 lo = make_uint4(
            __builtin_amdgcn_perm(rB[i].x, rA[i].x, SELLO),
            __builtin_amdgcn_perm(rB[i].x, rA[i].x, SELHI),
            __builtin_amdgcn_perm(rB[i].y, rA[i].y, SELLO),
            __builtin_amdgcn_perm(rB[i].y, rA[i].y, SELHI));
        uint4 hi = make_uint4(
            __builtin_amdgcn_perm(rB[i].z, rA[i].z, SELLO),
            __builtin_amdgcn_perm(rB[i].z, rA[i].z, SELHI),
            __builtin_amdgcn_perm(rB[i].w, rA[i].w, SELLO),
            0u);
        *reinterpret_cast<uint4*>(dst) = lo;
        *reinterpret_cast<uint4*>(dst + 4) = hi;
    }
}

// ---------------------------------------------------------------------------
// K3 = v7 (best measured: 43-44us across rounds 7/8/12). Whole-C blocks +
// pair-packed WsP + di ping-pong W prefetch.
// grid 256 tiles (4x16 pix); 512 thr = 64 pix x 8 cc (8ch each).
// ---------------------------------------------------------------------------
__global__ __launch_bounds__(512, 2) void k_agg(
        const u16* __restrict__ xh, const u32* __restrict__ WsP,
        float* __restrict__ out) {
    __shared__ u16 s_x[64 * 16 * 32];   // [ch][r][c] f16, 64KB
    int tb = blockIdx.x;
    int h0 = (tb >> 3) * 4, w0 = (tb & 7) * 16;
    int tid = threadIdx.x;

#pragma unroll
    for (int i = 0; i < 8; i++) {
        int it = tid + i * 512;
        int ch = it >> 6;
        int r = (it >> 2) & 15;
        int c0 = (it & 3) * 8;
        int gy = h0 - 6 + r, gx0 = w0 - 6 + c0;
        uint4 v = make_uint4(0u, 0u, 0u, 0u);
        if ((unsigned)gy < 128u) {
            const u16* src = xh + (size_t)ch * HW + gy * 128;
            if (gx0 >= 0 && gx0 <= 120) {
                v = *reinterpret_cast<const uint4*>(src + gx0);
            } else {
                auto pk = [&](int gx) -> u32 {
                    u32 lo = ((unsigned)gx < 128u) ? (u32)src[gx] : 0u;
                    u32 hi = ((unsigned)(gx + 1) < 128u) ? (u32)src[gx + 1] : 0u;
                    return lo | (hi << 16);
                };
                v = make_uint4(pk(gx0), pk(gx0 + 2), pk(gx0 + 4), pk(gx0 + 6));
            }
        }
        *reinterpret_cast<uint4*>(s_x + (ch * 16 + r) * 32 + c0) = v;
    }
    __syncthreads();

    int cc = tid >> 6, pix = tid & 63;
    int pr = pix >> 4, pc = pix & 15;
    int y = (h0 + pr) * 128 + (w0 + pc);
    const u32* wsrc = WsP + (size_t)y * 8;
    const u32* s_x32 = reinterpret_cast<const u32*>(s_x);
    u32 sh = (u32)(pc & 1) * 16;
    int base0 = cc * 8 * 256 + (pc >> 1);   // + q*256 + (pr+di)*16

    float acc[7][8];
#pragma unroll
    for (int k = 0; k < 7; k++)
#pragma unroll
        for (int q = 0; q < 8; q++) acc[k][q] = 0.f;

    auto loadW = [&](int di, uint4 (&A)[7], uint4 (&B)[7]) {
        const u32* wdi = wsrc + (size_t)(di * 7) * (HW * 8);
#pragma unroll
        for (int djp = 0; djp < 7; djp++) {
            const u32* wp = wdi + (size_t)djp * (HW * 8);
            A[djp] = *reinterpret_cast<const uint4*>(wp);
            B[djp] = *reinterpret_cast<const uint4*>(wp + 4);
        }
    };
    auto compute = [&](int di, const uint4 (&A)[7], const uint4 (&B)[7]) {
        int rowoff = (pr + di) * 16;
#pragma unroll
        for (int q = 0; q < 8; q++) {
            const u32* p = s_x32 + base0 + q * 256 + rowoff;
            u32 f0 = p[0], f1 = p[1], f2 = p[2], f3 = p[3];
            u32 f4 = p[4], f5 = p[5], f6 = p[6], f7 = p[7];
            u32 x2;
            x2 = __builtin_amdgcn_alignbit(f1, f0, sh);
            dot2acc(acc[0][q], A[0].x, x2); dot2acc(acc[1][q], A[0].y, x2);
            dot2acc(acc[2][q], A[0].z, x2); dot2acc(acc[3][q], A[0].w, x2);
            dot2acc(acc[4][q], B[0].x, x2); dot2acc(acc[5][q], B[0].y, x2);
            dot2acc(acc[6][q], B[0].z, x2);
            x2 = __builtin_amdgcn_alignbit(f2, f1, sh);
            dot2acc(acc[0][q], A[1].x, x2); dot2acc(acc[1][q], A[1].y, x2);
            dot2acc(acc[2][q], A[1].z, x2); dot2acc(acc[3][q], A[1].w, x2);
            dot2acc(acc[4][q], B[1].x, x2); dot2acc(acc[5][q], B[1].y, x2);
            dot2acc(acc[6][q], B[1].z, x2);
            x2 = __builtin_amdgcn_alignbit(f3, f2, sh);
            dot2acc(acc[0][q], A[2].x, x2); dot2acc(acc[1][q], A[2].y, x2);
            dot2acc(acc[2][q], A[2].z, x2); dot2acc(acc[3][q], A[2].w, x2);
            dot2acc(acc[4][q], B[2].x, x2); dot2acc(acc[5][q], B[2].y, x2);
            dot2acc(acc[6][q], B[2].z, x2);
            x2 = __builtin_amdgcn_alignbit(f4, f3, sh);
            dot2acc(acc[0][q], A[3].x, x2); dot2acc(acc[1][q], A[3].y, x2);
            dot2acc(acc[2][q], A[3].z, x2); dot2acc(acc[3][q], A[3].w, x2);
            dot2acc(acc[4][q], B[3].x, x2); dot2acc(acc[5][q], B[3].y, x2);
            dot2acc(acc[6][q], B[3].z, x2);
            x2 = __builtin_amdgcn_alignbit(f5, f4, sh);
            dot2acc(acc[0][q], A[4].x, x2); dot2acc(acc[1][q], A[4].y, x2);
            dot2acc(acc[2][q], A[4].z, x2); dot2acc(acc[3][q], A[4].w, x2);
            dot2acc(acc[4][q], B[4].x, x2); dot2acc(acc[5][q], B[4].y, x2);
            dot2acc(acc[6][q], B[4].z, x2);
            x2 = __builtin_amdgcn_alignbit(f6, f5, sh);
            dot2acc(acc[0][q], A[5].x, x2); dot2acc(acc[1][q], A[5].y, x2);
            dot2acc(acc[2][q], A[5].z, x2); dot2acc(acc[3][q], A[5].w, x2);
            dot2acc(acc[4][q], B[5].x, x2); dot2acc(acc[5][q], B[5].y, x2);
            dot2acc(acc[6][q], B[5].z, x2);
            x2 = __builtin_amdgcn_alignbit(f7, f6, sh);
            dot2acc(acc[0][q], A[6].x, x2); dot2acc(acc[1][q], A[6].y, x2);
            dot2acc(acc[2][q], A[6].z, x2); dot2acc(acc[3][q], A[6].w, x2);
            dot2acc(acc[4][q], B[6].x, x2); dot2acc(acc[5][q], B[6].y, x2);
            dot2acc(acc[6][q], B[6].z, x2);
        }
    };

    uint4 WA[7], WB[7], WC[7], WD[7];
    loadW(0, WA, WB);
#pragma unroll 1
    for (int di = 0; di < 12; di += 2) {
        loadW(di + 1, WC, WD);     // prefetch next di while computing current
        compute(di, WA, WB);
        loadW(di + 2, WA, WB);     // di+2 <= 12 always inside this loop
        compute(di + 1, WC, WD);
    }
    compute(12, WA, WB);

#pragma unroll
    for (int k = 0; k < 7; k++)
#pragma unroll
        for (int q = 0; q < 8; q++)
            out[(k * 64 + cc * 8 + q) * HW + y] = acc[k][q];
}

// ---------------------------------------------------------------------------
extern "C" void kernel_launch(void* const* d_in, const int* in_sizes, int n_in,
                              void* d_out, int out_size, void* d_ws, size_t ws_size,
                              hipStream_t stream) {
    (void)in_sizes; (void)n_in; (void)out_size; (void)ws_size;
    const float* x  = (const float*)d_in[0];
    const float* xe = (const float*)d_in[1];
    const float* ye = (const float*)d_in[2];
    const float* lt = (const float*)d_in[3];
    float* out = (float*)d_out;
    char* ws = (char*)d_ws;

    // layout (~121 MB). All disjoint.
    u16*    xh  = (u16*)(ws + 0);              //  2,097,152 B (f16 [64][128][128])
    float*  xeT = (float*)(ws + 2097152u);     //  2,097,152
    float*  yeT = (float*)(ws + 4194304u);     //  2,097,152
    u16*    Wkt = (u16*)(ws + 6291456u);       // 44,302,336 -> 50,593,792
    float*  lg  = (float*)(ws + 50593792u);    // 22,151,168 -> 72,744,960
    u32*    WsP = (u32*)(ws + 72744960u);      // 47,710,208 -> 120,455,168
    float*  nx2 = (float*)(ws + 120455168u);   //    131,072
    float*  ny  = (float*)(ws + 120586240u);   //     65,536
    float2* st  = (float2*)(ws + 120651776u);  //    131,072 -> ends 120,782,848

    k_prep<<<64, 256, 0, stream>>>(x, xe, ye, xh, xeT, yeT, nx2, ny);
    k_norms<<<64, 256, 0, stream>>>(ny, lt, st);
    k_logits<<<dim3(13, 64, 2), 1024, 0, stream>>>(xeT, yeT, nx2, lg);
    k_softmax<<<512, 256, 0, stream>>>(lg, st, Wkt);
    k_wsum<<<dim3(91, 16), 256, 0, stream>>>(Wkt, WsP);
    k_agg<<<256, 512, 0, stream>>>(xh, WsP, out);
}

// Round 15
// 133.113 us; speedup vs baseline: 1.2429x; 1.0175x over previous
//
#include <hip/hip_runtime.h>
#include <hip/hip_bf16.h>
#include <hip/hip_fp16.h>

// N3 aggregation: C=64, E=32, H=W=128, K=7, PS=7 (PR=3), WS=13 (WR=6), O=169
#define HW 16384

using u16 = unsigned short;
using u32 = unsigned int;
typedef __attribute__((ext_vector_type(2))) float f32x2;

__device__ __forceinline__ u16 f2h(float f) {
    __half h = __float2half(f);
    return __builtin_bit_cast(u16, h);
}
// acc += a.x*b.x + a.y*b.y  (f16 pairs, f32 accumulate)
__device__ __forceinline__ void dot2acc(float& acc, u32 a, u32 b) {
    asm("v_dot2_f32_f16 %0, %1, %2, %0" : "+v"(acc) : "v"(a), "v"(b));
}
__device__ __forceinline__ u32 hadd2u(u32 a, u32 b) {
    __half2 r = __hadd2(__builtin_bit_cast(__half2, a), __builtin_bit_cast(__half2, b));
    return __builtin_bit_cast(u32, r);
}
__device__ __forceinline__ u32 hsub2u(u32 a, u32 b) {
    __half2 r = __hsub2(__builtin_bit_cast(__half2, a), __builtin_bit_cast(__half2, b));
    return __builtin_bit_cast(u32, r);
}
#define SELLO 0x05040100u
#define SELHI 0x07060302u

// ---------------------------------------------------------------------------
// K0 v2: transposes + per-pixel HALF norms, 4x parallelism (grid 256).
// thread (g = tid>>6, l = tid&63): pixel y = blk*64+l, channels g*16..+15 of x
// and e-range g*8..+7 of xe/ye. Norms combined via 4x64 LDS tile.
// xe/ye stay f32 (f16 embeddings measured absmax 64 in round 13).
// ---------------------------------------------------------------------------
__global__ __launch_bounds__(256) void k_prep(
        const float* __restrict__ x, const float* __restrict__ xe,
        const float* __restrict__ ye,
        u16* __restrict__ xh, float* __restrict__ xeT,
        float* __restrict__ yeT, float* __restrict__ nx2, float* __restrict__ ny) {
    __shared__ float s_px[4][64], s_py[4][64];
    int tid = threadIdx.x;
    int g = tid >> 6, l = tid & 63;
    int y = blockIdx.x * 64 + l;

#pragma unroll
    for (int j = 0; j < 16; j++) {
        int c = g * 16 + j;
        xh[c * HW + y] = f2h(x[c * HW + y]);
    }

    float sx = 0.f, sy = 0.f;
#pragma unroll
    for (int e0 = 0; e0 < 8; e0 += 4) {
        int e = g * 8 + e0;
        float4 v = make_float4(xe[(e + 0) * HW + y], xe[(e + 1) * HW + y],
                               xe[(e + 2) * HW + y], xe[(e + 3) * HW + y]);
        *reinterpret_cast<float4*>(xeT + y * 32 + e) = v;
        sx += v.x * v.x + v.y * v.y + v.z * v.z + v.w * v.w;
        float4 u = make_float4(ye[(e + 0) * HW + y], ye[(e + 1) * HW + y],
                               ye[(e + 2) * HW + y], ye[(e + 3) * HW + y]);
        *reinterpret_cast<float4*>(yeT + y * 32 + e) = u;
        sy += u.x * u.x + u.y * u.y + u.z * u.z + u.w * u.w;
    }
    s_px[g][l] = sx;
    s_py[g][l] = sy;
    __syncthreads();
    if (tid < 64) {
        nx2[y] = s_px[0][l] + s_px[1][l];            // e 0..15
        nx2[HW + y] = s_px[2][l] + s_px[3][l];       // e 16..31
        ny[y] = s_py[0][l] + s_py[1][l] + s_py[2][l] + s_py[3][l];
    }
}

// ---------------------------------------------------------------------------
// K0b: st[y] = (tinv, tinv*Sy), tinv = exp(-boxsum(lt)/49), Sy = boxsum(ny).
// ---------------------------------------------------------------------------
__global__ __launch_bounds__(256) void k_norms(
        const float* __restrict__ ny, const float* __restrict__ lt,
        float2* __restrict__ st) {
    int y = blockIdx.x * 256 + threadIdx.x;
    int py = y >> 7, px = y & 127;
    float s = 0.f, t = 0.f;
    for (int dy = -3; dy <= 3; dy++)
        for (int dx = -3; dx <= 3; dx++) {
            int yy = py + dy, xx = px + dx;
            if ((unsigned)yy < 128u && (unsigned)xx < 128u) {
                int p = yy * 128 + xx;
                s += ny[p];
                t += lt[p];
            }
        }
    float tinv = __expf(-t * (1.0f / 49.0f));
    st[y] = make_float2(tinv, tinv * s);
}

// ---------------------------------------------------------------------------
// K1 v5: E-split partial logits, f32 embeddings (precision-critical) +
// vectorized 7-tap sums. grid (13 di, 64 tiles, 2 e-halves), 1024 thr.
// lg[h][o][y] = boxsum_z( nx_h(z+o) - 2 * ye_h(z) . xe_h(z+o) )  (raw)
// ---------------------------------------------------------------------------
__global__ __launch_bounds__(1024) void k_logits(
        const float* __restrict__ xeT, const float* __restrict__ yeT,
        const float* __restrict__ nx2, float* __restrict__ lg) {
#pragma clang fp contract(fast)
    __shared__ __align__(16) char arena[78320];
    float* s_xe = (float*)arena;              // 748 cells * 16 dw, chunk-swizzled
    float* s_nx = (float*)(arena + 47872);    // 748 f32
    float* s_d2 = (float*)(arena + 50864);    // [13][22][24] f32
    float* s_hs = (float*)arena;              // overlay: [13][22][16] f32

    int di = blockIdx.x;
    int tile = blockIdx.y;
    int h = blockIdx.z;                       // e-half
    int h0 = (tile >> 3) * 16, w0 = (tile & 7) * 16;
    int gr0 = h0 + di - 9, gc0 = w0 - 9;
    int tid = threadIdx.x;

    for (int idx = tid; idx < 748 * 4; idx += 1024) {
        int cell = idx >> 2, q = idx & 3;
        int r = cell / 34, c = cell - r * 34;
        int gy = gr0 + r, gx = gc0 + c;
        float4 v = make_float4(0.f, 0.f, 0.f, 0.f);
        if ((unsigned)gy < 128u && (unsigned)gx < 128u)
            v = *reinterpret_cast<const float4*>(
                    xeT + (size_t)(gy * 128 + gx) * 32 + h * 16 + q * 4);
        *reinterpret_cast<float4*>(s_xe + cell * 16 + ((q ^ (cell & 3)) << 2)) = v;
    }
    for (int idx = tid; idx < 748; idx += 1024) {
        int r = idx / 34, c = idx - r * 34;
        int gy = gr0 + r, gx = gc0 + c;
        float v = 0.f;
        if ((unsigned)gy < 128u && (unsigned)gx < 128u)
            v = nx2[h * HW + gy * 128 + gx];
        s_nx[idx] = v;
    }
    __syncthreads();

    if (tid < 484) {
        int zr = tid / 22, zc = tid - zr * 22;
        int gy = h0 - 3 + zr, gx = w0 - 3 + zc;
        bool zin = ((unsigned)gy < 128u) && ((unsigned)gx < 128u);
        f32x2 yv[8];
#pragma unroll
        for (int j = 0; j < 8; j++) yv[j] = (f32x2){0.f, 0.f};
        if (zin) {
            const float* yp = yeT + (size_t)(gy * 128 + gx) * 32 + h * 16;
#pragma unroll
            for (int j = 0; j < 4; j++) {
                float4 t = *reinterpret_cast<const float4*>(yp + j * 4);
                yv[2 * j] = (f32x2){t.x, t.y};
                yv[2 * j + 1] = (f32x2){t.z, t.w};
            }
        }
        int cell0 = zr * 34 + zc;
#pragma unroll
        for (int dj = 0; dj < 13; dj++) {
            int cell = cell0 + dj;
            const float* bp = s_xe + cell * 16;
            int sw = cell & 3;
            f32x2 a0 = {0.f, 0.f}, a1 = {0.f, 0.f};
#pragma unroll
            for (int q = 0; q < 4; q++) {
                float4 xv = *reinterpret_cast<const float4*>(bp + ((q ^ sw) << 2));
                a0 += ((f32x2){xv.x, xv.y}) * yv[2 * q];
                a1 += ((f32x2){xv.z, xv.w}) * yv[2 * q + 1];
            }
            float cr = a0.x + a0.y + a1.x + a1.y;
            float d2v = fmaf(-2.f, cr, s_nx[cell]);
            s_d2[dj * 528 + zr * 24 + zc] = zin ? d2v : 0.f;
        }
    }
    __syncthreads();

    // horizontal 7-tap, 4 outputs/thread via sliding window: 13*22*4 units
    for (int idx = tid; idx < 1144; idx += 1024) {
        int dj = idx / 88, rem = idx - dj * 88;
        int r = rem >> 2, c4 = (rem & 3) * 4;
        const float* p = s_d2 + dj * 528 + r * 24 + c4;
        float4 pa = *reinterpret_cast<const float4*>(p);
        float4 pb = *reinterpret_cast<const float4*>(p + 4);
        float4 pc = *reinterpret_cast<const float4*>(p + 8);
        float h0s = pa.x + pa.y + pa.z + pa.w + pb.x + pb.y + pb.z;
        float h1s = h0s - pa.x + pb.w;
        float h2s = h1s - pa.y + pc.x;
        float h3s = h2s - pa.z + pc.y;
        *reinterpret_cast<float4*>(s_hs + (dj * 22 + r) * 16 + c4) =
            make_float4(h0s, h1s, h2s, h3s);
    }
    __syncthreads();

    // vertical 7-tap + store raw partial boxsum: 13*16*4 units, float4 each
    for (int idx = tid; idx < 832; idx += 1024) {
        int dj = idx >> 6, rem = idx & 63;
        int i = rem >> 2, j4 = (rem & 3) * 4;
        const float* p = s_hs + (dj * 22 + i) * 16 + j4;
        float4 s = *reinterpret_cast<const float4*>(p);
#pragma unroll
        for (int d = 1; d < 7; d++) {
            float4 t = *reinterpret_cast<const float4*>(p + d * 16);
            s.x += t.x; s.y += t.y; s.z += t.z; s.w += t.w;
        }
        int y = (h0 + i) * 128 + (w0 + j4);
        *reinterpret_cast<float4*>(
            lg + ((size_t)h * 169 + di * 13 + dj) * HW + y) = s;
    }
}

// ---------------------------------------------------------------------------
// K2: K=7 rounds of exclusion softmax over O=169. grid 512 x 256.
// Sums the two e-half partials and applies -(tinv*bs + tinv*Sy) during stage.
// ---------------------------------------------------------------------------
__global__ __launch_bounds__(256) void k_softmax(
        const float* __restrict__ lg, const float2* __restrict__ st,
        u16* __restrict__ Wkt) {
    __shared__ float s_lg[169 * 34];
    int tid = threadIdx.x;
    int y0 = blockIdx.x * 32;
    for (int idx = tid; idx < 169 * 32; idx += 256) {
        int o = idx >> 5, p = idx & 31;
        s_lg[o * 34 + p] = lg[(size_t)o * HW + y0 + p]
                         + lg[(size_t)(169 + o) * HW + y0 + p];
    }
    __syncthreads();
    int pix = tid >> 3, t = tid & 7;
    int y = y0 + pix;
    float2 ab = st[y];
    float l[22];
#pragma unroll
    for (int j = 0; j < 22; j++) {
        int o = t + 8 * j;
        l[j] = (o < 169) ? -fmaf(ab.x, s_lg[o * 34 + pix], ab.y) : -3e38f;
    }
    u32 wp0[22], wp1[22], wp2[22], wp3[22];
#pragma unroll
    for (int j = 0; j < 22; j++) { wp0[j] = 0u; wp1[j] = 0u; wp2[j] = 0u; wp3[j] = 0u; }

    float e[22];
#pragma unroll
    for (int k = 0; k < 7; k++) {
        float m = -3e38f;
#pragma unroll
        for (int j = 0; j < 22; j++) m = fmaxf(m, l[j]);
        m = fmaxf(m, __shfl_xor(m, 1));
        m = fmaxf(m, __shfl_xor(m, 2));
        m = fmaxf(m, __shfl_xor(m, 4));
        float s = 0.f;
#pragma unroll
        for (int j = 0; j < 22; j++) { e[j] = __expf(l[j] - m); s += e[j]; }
        s += __shfl_xor(s, 1);
        s += __shfl_xor(s, 2);
        s += __shfl_xor(s, 4);
        float rs = 1.0f / s;
#pragma unroll
        for (int j = 0; j < 22; j++) {
            float w = e[j] * rs;
            u32 hh = (u32)f2h(w);
            if (k == 0) wp0[j] |= hh;
            else if (k == 1) wp0[j] |= hh << 16;
            else if (k == 2) wp1[j] |= hh;
            else if (k == 3) wp1[j] |= hh << 16;
            else if (k == 4) wp2[j] |= hh;
            else if (k == 5) wp2[j] |= hh << 16;
            else wp3[j] |= hh;
            if (k < 6) l[j] += __logf(fmaxf(1.0f - w, 1e-6f));
        }
    }
#pragma unroll
    for (int j = 0; j < 22; j++) {
        int o = t + 8 * j;
        if (o < 169)
            *reinterpret_cast<uint4*>(Wkt + ((size_t)o * HW + y) * 8) =
                make_uint4(wp0[j], wp1[j], wp2[j], wp3[j]);
    }
}

// ---------------------------------------------------------------------------
// K2b v3: 7x7 boxsum of Wkt(f16) -> PAIR-PACKED WsP[o2][y][8 u32].
// Vert phase now sliding-window: 304 units x 4 out-rows, 10 b128 reads per
// unit (was 28 across 4 cells). Unit map keeps v2's conflict-free c-major
// lane order. Horiz phase unchanged (measured fine).
// ---------------------------------------------------------------------------
__global__ __launch_bounds__(256) void k_wsum(
        const u16* __restrict__ Wkt, u32* __restrict__ WsP) {
    __shared__ u16 s_w[38 * 39 * 8];   // [row][col pad39][k8]
    __shared__ u16 s_v[32 * 38 * 8];   // [outrow][col][k8] f16 vertical sums
    int o2 = blockIdx.x;
    int di = o2 / 7, djp = o2 - di * 7;
    int oA = di * 13 + 2 * djp;
    bool hasB = (djp < 6);
    int tile = blockIdx.y;
    int h0 = (tile >> 2) * 32, w0 = (tile & 3) * 32;
    int tid = threadIdx.x;

    auto stage = [&](int o) {
        const u16* src = Wkt + (size_t)o * (HW * 8);
        for (int idx = tid; idx < 38 * 38; idx += 256) {
            int r = idx / 38, c = idx - r * 38;
            int gy = h0 - 3 + r, gx = w0 - 3 + c;
            uint4 v = make_uint4(0u, 0u, 0u, 0u);
            if ((unsigned)gy < 128u && (unsigned)gx < 128u)
                v = *reinterpret_cast<const uint4*>(src + (gy * 128 + gx) * 8);
            *reinterpret_cast<uint4*>(s_w + (r * 39 + c) * 8) = v;
        }
    };
    auto vert = [&]() {
        for (int u = tid; u < 304; u += 256) {   // 8 groups(4 out-rows) x 38 cols
            int g = u / 38, c = u - g * 38;
            int r0 = g * 4;
            uint4 q[10];
#pragma unroll
            for (int d = 0; d < 10; d++)
                q[d] = *reinterpret_cast<const uint4*>(s_w + ((r0 + d) * 39 + c) * 8);
            uint4 s = q[0];
#pragma unroll
            for (int d = 1; d < 7; d++) {
                s.x = hadd2u(s.x, q[d].x); s.y = hadd2u(s.y, q[d].y);
                s.z = hadd2u(s.z, q[d].z); s.w = hadd2u(s.w, q[d].w);
            }
            *reinterpret_cast<uint4*>(s_v + (r0 * 38 + c) * 8) = s;
#pragma unroll
            for (int j = 1; j < 4; j++) {
                s.x = hadd2u(hsub2u(s.x, q[j - 1].x), q[j + 6].x);
                s.y = hadd2u(hsub2u(s.y, q[j - 1].y), q[j + 6].y);
                s.z = hadd2u(hsub2u(s.z, q[j - 1].z), q[j + 6].z);
                s.w = hadd2u(hsub2u(s.w, q[j - 1].w), q[j + 6].w);
                *reinterpret_cast<uint4*>(s_v + ((r0 + j) * 38 + c) * 8) = s;
            }
        }
    };
    auto horiz = [&](uint4 (&rr)[4]) {
#pragma unroll
        for (int i = 0; i < 4; i++) {              // 32 rows x 32 out-cols
            int u = tid + i * 256;
            int r = u >> 5, cx = u & 31;
            __half2 s0 = __builtin_bit_cast(__half2, 0u);
            __half2 s1 = s0, s2 = s0, s3 = s0;
#pragma unroll
            for (int d = 0; d < 7; d++) {
                uint4 q = *reinterpret_cast<const uint4*>(s_v + (r * 38 + cx + d) * 8);
                s0 = __hadd2(s0, __builtin_bit_cast(__half2, q.x));
                s1 = __hadd2(s1, __builtin_bit_cast(__half2, q.y));
                s2 = __hadd2(s2, __builtin_bit_cast(__half2, q.z));
                s3 = __hadd2(s3, __builtin_bit_cast(__half2, q.w));
            }
            rr[i] = make_uint4(
                __builtin_bit_cast(u32, s0), __builtin_bit_cast(u32, s1),
                __builtin_bit_cast(u32, s2), __builtin_bit_cast(u32, s3));
        }
    };

    uint4 rA[4], rB[4];
#pragma unroll
    for (int i = 0; i < 4; i++) rB[i] = make_uint4(0u, 0u, 0u, 0u);

    stage(oA);
    __syncthreads();
    vert();
    __syncthreads();
    horiz(rA);
    if (hasB) {
        __syncthreads();           // rA-horiz reads done; safe to overwrite s_w
        stage(oA + 1);
        __syncthreads();
        vert();
        __syncthreads();
        horiz(rB);
    }

#pragma unroll
    for (int i = 0; i < 4; i++) {
        int u = tid + i * 256;
        int r = u >> 5, cx = u & 31;
        int y = (h0 + r) * 128 + (w0 + cx);
        u32* dst = WsP + ((size_t)o2 * HW + y) * 8;
        uint4 lo = make_uint4(
            __builtin_amdgcn_perm(rB[i].x, rA[i].x, SELLO),
            __builtin_amdgcn_perm(rB[i].x, rA[i].x, SELHI),
            __builtin_amdgcn_perm(rB[i].y, rA[i].y, SELLO),
            __builtin_amdgcn_perm(rB[i].y, rA[i].y, SELHI));
        uint4 hi = make_uint4(
            __builtin_amdgcn_perm(rB[i].z, rA[i].z, SELLO),
            __builtin_amdgcn_perm(rB[i].z, rA[i].z, SELHI),
            __builtin_amdgcn_perm(rB[i].w, rA[i].w, SELLO),
            0u);
        *reinterpret_cast<uint4*>(dst) = lo;
        *reinterpret_cast<uint4*>(dst + 4) = hi;
    }
}

// ---------------------------------------------------------------------------
// K3 = v7 (best measured: 43-44us across rounds 7/8/12/14). Whole-C blocks +
// pair-packed WsP + di ping-pong W prefetch.
// grid 256 tiles (4x16 pix); 512 thr = 64 pix x 8 cc (8ch each).
// ---------------------------------------------------------------------------
__global__ __launch_bounds__(512, 2) void k_agg(
        const u16* __restrict__ xh, const u32* __restrict__ WsP,
        float* __restrict__ out) {
    __shared__ u16 s_x[64 * 16 * 32];   // [ch][r][c] f16, 64KB
    int tb = blockIdx.x;
    int h0 = (tb >> 3) * 4, w0 = (tb & 7) * 16;
    int tid = threadIdx.x;

#pragma unroll
    for (int i = 0; i < 8; i++) {
        int it = tid + i * 512;
        int ch = it >> 6;
        int r = (it >> 2) & 15;
        int c0 = (it & 3) * 8;
        int gy = h0 - 6 + r, gx0 = w0 - 6 + c0;
        uint4 v = make_uint4(0u, 0u, 0u, 0u);
        if ((unsigned)gy < 128u) {
            const u16* src = xh + (size_t)ch * HW + gy * 128;
            if (gx0 >= 0 && gx0 <= 120) {
                v = *reinterpret_cast<const uint4*>(src + gx0);
            } else {
                auto pk = [&](int gx) -> u32 {
                    u32 lo = ((unsigned)gx < 128u) ? (u32)src[gx] : 0u;
                    u32 hi = ((unsigned)(gx + 1) < 128u) ? (u32)src[gx + 1] : 0u;
                    return lo | (hi << 16);
                };
                v = make_uint4(pk(gx0), pk(gx0 + 2), pk(gx0 + 4), pk(gx0 + 6));
            }
        }
        *reinterpret_cast<uint4*>(s_x + (ch * 16 + r) * 32 + c0) = v;
    }
    __syncthreads();

    int cc = tid >> 6, pix = tid & 63;
    int pr = pix >> 4, pc = pix & 15;
    int y = (h0 + pr) * 128 + (w0 + pc);
    const u32* wsrc = WsP + (size_t)y * 8;
    const u32* s_x32 = reinterpret_cast<const u32*>(s_x);
    u32 sh = (u32)(pc & 1) * 16;
    int base0 = cc * 8 * 256 + (pc >> 1);   // + q*256 + (pr+di)*16

    float acc[7][8];
#pragma unroll
    for (int k = 0; k < 7; k++)
#pragma unroll
        for (int q = 0; q < 8; q++) acc[k][q] = 0.f;

    auto loadW = [&](int di, uint4 (&A)[7], uint4 (&B)[7]) {
        const u32* wdi = wsrc + (size_t)(di * 7) * (HW * 8);
#pragma unroll
        for (int djp = 0; djp < 7; djp++) {
            const u32* wp = wdi + (size_t)djp * (HW * 8);
            A[djp] = *reinterpret_cast<const uint4*>(wp);
            B[djp] = *reinterpret_cast<const uint4*>(wp + 4);
        }
    };
    auto compute = [&](int di, const uint4 (&A)[7], const uint4 (&B)[7]) {
        int rowoff = (pr + di) * 16;
#pragma unroll
        for (int q = 0; q < 8; q++) {
            const u32* p = s_x32 + base0 + q * 256 + rowoff;
            u32 f0 = p[0], f1 = p[1], f2 = p[2], f3 = p[3];
            u32 f4 = p[4], f5 = p[5], f6 = p[6], f7 = p[7];
            u32 x2;
            x2 = __builtin_amdgcn_alignbit(f1, f0, sh);
            dot2acc(acc[0][q], A[0].x, x2); dot2acc(acc[1][q], A[0].y, x2);
            dot2acc(acc[2][q], A[0].z, x2); dot2acc(acc[3][q], A[0].w, x2);
            dot2acc(acc[4][q], B[0].x, x2); dot2acc(acc[5][q], B[0].y, x2);
            dot2acc(acc[6][q], B[0].z, x2);
            x2 = __builtin_amdgcn_alignbit(f2, f1, sh);
            dot2acc(acc[0][q], A[1].x, x2); dot2acc(acc[1][q], A[1].y, x2);
            dot2acc(acc[2][q], A[1].z, x2); dot2acc(acc[3][q], A[1].w, x2);
            dot2acc(acc[4][q], B[1].x, x2); dot2acc(acc[5][q], B[1].y, x2);
            dot2acc(acc[6][q], B[1].z, x2);
            x2 = __builtin_amdgcn_alignbit(f3, f2, sh);
            dot2acc(acc[0][q], A[2].x, x2); dot2acc(acc[1][q], A[2].y, x2);
            dot2acc(acc[2][q], A[2].z, x2); dot2acc(acc[3][q], A[2].w, x2);
            dot2acc(acc[4][q], B[2].x, x2); dot2acc(acc[5][q], B[2].y, x2);
            dot2acc(acc[6][q], B[2].z, x2);
            x2 = __builtin_amdgcn_alignbit(f4, f3, sh);
            dot2acc(acc[0][q], A[3].x, x2); dot2acc(acc[1][q], A[3].y, x2);
            dot2acc(acc[2][q], A[3].z, x2); dot2acc(acc[3][q], A[3].w, x2);
            dot2acc(acc[4][q], B[3].x, x2); dot2acc(acc[5][q], B[3].y, x2);
            dot2acc(acc[6][q], B[3].z, x2);
            x2 = __builtin_amdgcn_alignbit(f5, f4, sh);
            dot2acc(acc[0][q], A[4].x, x2); dot2acc(acc[1][q], A[4].y, x2);
            dot2acc(acc[2][q], A[4].z, x2); dot2acc(acc[3][q], A[4].w, x2);
            dot2acc(acc[4][q], B[4].x, x2); dot2acc(acc[5][q], B[4].y, x2);
            dot2acc(acc[6][q], B[4].z, x2);
            x2 = __builtin_amdgcn_alignbit(f6, f5, sh);
            dot2acc(acc[0][q], A[5].x, x2); dot2acc(acc[1][q], A[5].y, x2);
            dot2acc(acc[2][q], A[5].z, x2); dot2acc(acc[3][q], A[5].w, x2);
            dot2acc(acc[4][q], B[5].x, x2); dot2acc(acc[5][q], B[5].y, x2);
            dot2acc(acc[6][q], B[5].z, x2);
            x2 = __builtin_amdgcn_alignbit(f7, f6, sh);
            dot2acc(acc[0][q], A[6].x, x2); dot2acc(acc[1][q], A[6].y, x2);
            dot2acc(acc[2][q], A[6].z, x2); dot2acc(acc[3][q], A[6].w, x2);
            dot2acc(acc[4][q], B[6].x, x2); dot2acc(acc[5][q], B[6].y, x2);
            dot2acc(acc[6][q], B[6].z, x2);
        }
    };

    uint4 WA[7], WB[7], WC[7], WD[7];
    loadW(0, WA, WB);
#pragma unroll 1
    for (int di = 0; di < 12; di += 2) {
        loadW(di + 1, WC, WD);     // prefetch next di while computing current
        compute(di, WA, WB);
        loadW(di + 2, WA, WB);     // di+2 <= 12 always inside this loop
        compute(di + 1, WC, WD);
    }
    compute(12, WA, WB);

#pragma unroll
    for (int k = 0; k < 7; k++)
#pragma unroll
        for (int q = 0; q < 8; q++)
            out[(k * 64 + cc * 8 + q) * HW + y] = acc[k][q];
}

// ---------------------------------------------------------------------------
extern "C" void kernel_launch(void* const* d_in, const int* in_sizes, int n_in,
                              void* d_out, int out_size, void* d_ws, size_t ws_size,
                              hipStream_t stream) {
    (void)in_sizes; (void)n_in; (void)out_size; (void)ws_size;
    const float* x  = (const float*)d_in[0];
    const float* xe = (const float*)d_in[1];
    const float* ye = (const float*)d_in[2];
    const float* lt = (const float*)d_in[3];
    float* out = (float*)d_out;
    char* ws = (char*)d_ws;

    // layout (~121 MB). All disjoint.
    u16*    xh  = (u16*)(ws + 0);              //  2,097,152 B (f16 [64][128][128])
    float*  xeT = (float*)(ws + 2097152u);     //  2,097,152
    float*  yeT = (float*)(ws + 4194304u);     //  2,097,152
    u16*    Wkt = (u16*)(ws + 6291456u);       // 44,302,336 -> 50,593,792
    float*  lg  = (float*)(ws + 50593792u);    // 22,151,168 -> 72,744,960
    u32*    WsP = (u32*)(ws + 72744960u);      // 47,710,208 -> 120,455,168
    float*  nx2 = (float*)(ws + 120455168u);   //    131,072
    float*  ny  = (float*)(ws + 120586240u);   //     65,536
    float2* st  = (float2*)(ws + 120651776u);  //    131,072 -> ends 120,782,848

    k_prep<<<256, 256, 0, stream>>>(x, xe, ye, xh, xeT, yeT, nx2, ny);
    k_norms<<<64, 256, 0, stream>>>(ny, lt, st);
    k_logits<<<dim3(13, 64, 2), 1024, 0, stream>>>(xeT, yeT, nx2, lg);
    k_softmax<<<512, 256, 0, stream>>>(lg, st, Wkt);
    k_wsum<<<dim3(91, 16), 256, 0, stream>>>(Wkt, WsP);
    k_agg<<<256, 512, 0, stream>>>(xh, WsP, out);
}

// Round 16
// 131.657 us; speedup vs baseline: 1.2567x; 1.0111x over previous
//
#include <hip/hip_runtime.h>
#include <hip/hip_bf16.h>
#include <hip/hip_fp16.h>

// N3 aggregation: C=64, E=32, H=W=128, K=7, PS=7 (PR=3), WS=13 (WR=6), O=169
#define HW 16384

using u16 = unsigned short;
using u32 = unsigned int;
typedef __attribute__((ext_vector_type(2))) float f32x2;

__device__ __forceinline__ u16 f2h(float f) {
    __half h = __float2half(f);
    return __builtin_bit_cast(u16, h);
}
// acc += a.x*b.x + a.y*b.y  (f16 pairs, f32 accumulate)
__device__ __forceinline__ void dot2acc(float& acc, u32 a, u32 b) {
    asm("v_dot2_f32_f16 %0, %1, %2, %0" : "+v"(acc) : "v"(a), "v"(b));
}
__device__ __forceinline__ u32 hadd2u(u32 a, u32 b) {
    __half2 r = __hadd2(__builtin_bit_cast(__half2, a), __builtin_bit_cast(__half2, b));
    return __builtin_bit_cast(u32, r);
}
__device__ __forceinline__ u32 hsub2u(u32 a, u32 b) {
    __half2 r = __hsub2(__builtin_bit_cast(__half2, a), __builtin_bit_cast(__half2, b));
    return __builtin_bit_cast(u32, r);
}
#define SELLO 0x05040100u
#define SELHI 0x07060302u

// ---------------------------------------------------------------------------
// K0 v2: transposes + per-pixel HALF norms, grid 256.
// xe/ye stay f32 (f16 embeddings measured absmax 64 in round 13).
// ---------------------------------------------------------------------------
__global__ __launch_bounds__(256) void k_prep(
        const float* __restrict__ x, const float* __restrict__ xe,
        const float* __restrict__ ye,
        u16* __restrict__ xh, float* __restrict__ xeT,
        float* __restrict__ yeT, float* __restrict__ nx2, float* __restrict__ ny) {
    __shared__ float s_px[4][64], s_py[4][64];
    int tid = threadIdx.x;
    int g = tid >> 6, l = tid & 63;
    int y = blockIdx.x * 64 + l;

#pragma unroll
    for (int j = 0; j < 16; j++) {
        int c = g * 16 + j;
        xh[c * HW + y] = f2h(x[c * HW + y]);
    }

    float sx = 0.f, sy = 0.f;
#pragma unroll
    for (int e0 = 0; e0 < 8; e0 += 4) {
        int e = g * 8 + e0;
        float4 v = make_float4(xe[(e + 0) * HW + y], xe[(e + 1) * HW + y],
                               xe[(e + 2) * HW + y], xe[(e + 3) * HW + y]);
        *reinterpret_cast<float4*>(xeT + y * 32 + e) = v;
        sx += v.x * v.x + v.y * v.y + v.z * v.z + v.w * v.w;
        float4 u = make_float4(ye[(e + 0) * HW + y], ye[(e + 1) * HW + y],
                               ye[(e + 2) * HW + y], ye[(e + 3) * HW + y]);
        *reinterpret_cast<float4*>(yeT + y * 32 + e) = u;
        sy += u.x * u.x + u.y * u.y + u.z * u.z + u.w * u.w;
    }
    s_px[g][l] = sx;
    s_py[g][l] = sy;
    __syncthreads();
    if (tid < 64) {
        nx2[y] = s_px[0][l] + s_px[1][l];            // e 0..15
        nx2[HW + y] = s_px[2][l] + s_px[3][l];       // e 16..31
        ny[y] = s_py[0][l] + s_py[1][l] + s_py[2][l] + s_py[3][l];
    }
}

// ---------------------------------------------------------------------------
// K1 v5: E-split partial logits, f32 embeddings (precision-critical) +
// vectorized 7-tap sums. grid (13 di, 64 tiles, 2 e-halves), 1024 thr.
// lg[h][o][y] = boxsum_z( nx_h(z+o) - 2 * ye_h(z) . xe_h(z+o) )  (raw)
// ---------------------------------------------------------------------------
__global__ __launch_bounds__(1024) void k_logits(
        const float* __restrict__ xeT, const float* __restrict__ yeT,
        const float* __restrict__ nx2, float* __restrict__ lg) {
#pragma clang fp contract(fast)
    __shared__ __align__(16) char arena[78320];
    float* s_xe = (float*)arena;              // 748 cells * 16 dw, chunk-swizzled
    float* s_nx = (float*)(arena + 47872);    // 748 f32
    float* s_d2 = (float*)(arena + 50864);    // [13][22][24] f32
    float* s_hs = (float*)arena;              // overlay: [13][22][16] f32

    int di = blockIdx.x;
    int tile = blockIdx.y;
    int h = blockIdx.z;                       // e-half
    int h0 = (tile >> 3) * 16, w0 = (tile & 7) * 16;
    int gr0 = h0 + di - 9, gc0 = w0 - 9;
    int tid = threadIdx.x;

    for (int idx = tid; idx < 748 * 4; idx += 1024) {
        int cell = idx >> 2, q = idx & 3;
        int r = cell / 34, c = cell - r * 34;
        int gy = gr0 + r, gx = gc0 + c;
        float4 v = make_float4(0.f, 0.f, 0.f, 0.f);
        if ((unsigned)gy < 128u && (unsigned)gx < 128u)
            v = *reinterpret_cast<const float4*>(
                    xeT + (size_t)(gy * 128 + gx) * 32 + h * 16 + q * 4);
        *reinterpret_cast<float4*>(s_xe + cell * 16 + ((q ^ (cell & 3)) << 2)) = v;
    }
    for (int idx = tid; idx < 748; idx += 1024) {
        int r = idx / 34, c = idx - r * 34;
        int gy = gr0 + r, gx = gc0 + c;
        float v = 0.f;
        if ((unsigned)gy < 128u && (unsigned)gx < 128u)
            v = nx2[h * HW + gy * 128 + gx];
        s_nx[idx] = v;
    }
    __syncthreads();

    if (tid < 484) {
        int zr = tid / 22, zc = tid - zr * 22;
        int gy = h0 - 3 + zr, gx = w0 - 3 + zc;
        bool zin = ((unsigned)gy < 128u) && ((unsigned)gx < 128u);
        f32x2 yv[8];
#pragma unroll
        for (int j = 0; j < 8; j++) yv[j] = (f32x2){0.f, 0.f};
        if (zin) {
            const float* yp = yeT + (size_t)(gy * 128 + gx) * 32 + h * 16;
#pragma unroll
            for (int j = 0; j < 4; j++) {
                float4 t = *reinterpret_cast<const float4*>(yp + j * 4);
                yv[2 * j] = (f32x2){t.x, t.y};
                yv[2 * j + 1] = (f32x2){t.z, t.w};
            }
        }
        int cell0 = zr * 34 + zc;
#pragma unroll
        for (int dj = 0; dj < 13; dj++) {
            int cell = cell0 + dj;
            const float* bp = s_xe + cell * 16;
            int sw = cell & 3;
            f32x2 a0 = {0.f, 0.f}, a1 = {0.f, 0.f};
#pragma unroll
            for (int q = 0; q < 4; q++) {
                float4 xv = *reinterpret_cast<const float4*>(bp + ((q ^ sw) << 2));
                a0 += ((f32x2){xv.x, xv.y}) * yv[2 * q];
                a1 += ((f32x2){xv.z, xv.w}) * yv[2 * q + 1];
            }
            float cr = a0.x + a0.y + a1.x + a1.y;
            float d2v = fmaf(-2.f, cr, s_nx[cell]);
            s_d2[dj * 528 + zr * 24 + zc] = zin ? d2v : 0.f;
        }
    }
    __syncthreads();

    // horizontal 7-tap, 4 outputs/thread via sliding window: 13*22*4 units
    for (int idx = tid; idx < 1144; idx += 1024) {
        int dj = idx / 88, rem = idx - dj * 88;
        int r = rem >> 2, c4 = (rem & 3) * 4;
        const float* p = s_d2 + dj * 528 + r * 24 + c4;
        float4 pa = *reinterpret_cast<const float4*>(p);
        float4 pb = *reinterpret_cast<const float4*>(p + 4);
        float4 pc = *reinterpret_cast<const float4*>(p + 8);
        float h0s = pa.x + pa.y + pa.z + pa.w + pb.x + pb.y + pb.z;
        float h1s = h0s - pa.x + pb.w;
        float h2s = h1s - pa.y + pc.x;
        float h3s = h2s - pa.z + pc.y;
        *reinterpret_cast<float4*>(s_hs + (dj * 22 + r) * 16 + c4) =
            make_float4(h0s, h1s, h2s, h3s);
    }
    __syncthreads();

    // vertical 7-tap + store raw partial boxsum: 13*16*4 units, float4 each
    for (int idx = tid; idx < 832; idx += 1024) {
        int dj = idx >> 6, rem = idx & 63;
        int i = rem >> 2, j4 = (rem & 3) * 4;
        const float* p = s_hs + (dj * 22 + i) * 16 + j4;
        float4 s = *reinterpret_cast<const float4*>(p);
#pragma unroll
        for (int d = 1; d < 7; d++) {
            float4 t = *reinterpret_cast<const float4*>(p + d * 16);
            s.x += t.x; s.y += t.y; s.z += t.z; s.w += t.w;
        }
        int y = (h0 + i) * 128 + (w0 + j4);
        *reinterpret_cast<float4*>(
            lg + ((size_t)h * 169 + di * 13 + dj) * HW + y) = s;
    }
}

// ---------------------------------------------------------------------------
// K2 v2: exclusion softmax + inlined temperature/Sy (k_norms folded in).
// grid 512 (XCD-remapped so blocks of image-tile t2 run on XCD t2%8, matching
// k_wsum's consumers of Wkt). 32 pixels/block.
// ---------------------------------------------------------------------------
__global__ __launch_bounds__(256) void k_softmax(
        const float* __restrict__ lg, const float* __restrict__ ny,
        const float* __restrict__ lt, u16* __restrict__ Wkt) {
    __shared__ float s_lg[169 * 34];
    __shared__ float2 s_ab[32];
    int tid = threadIdx.x;
    // bijective XCD remap: lbid -> (t2 with t2%8 == lbid%8, rr)
    int lbid = blockIdx.x;
    int cls = lbid & 7, i0 = lbid >> 3;
    int t2 = cls + 8 * (i0 & 1);
    int rr = i0 >> 1;                       // 0..31
    int tr = t2 >> 2, q = t2 & 3;
    int r = tr * 32 + rr;                   // pixel row
    int y0 = r * 128 + q * 32;              // 32 consecutive pixels

    if (tid < 32) {                         // st for pixel y0+tid (was k_norms)
        int px = q * 32 + tid;
        float s = 0.f, t = 0.f;
        for (int dy = -3; dy <= 3; dy++) {
            int yy = r + dy;
            if ((unsigned)yy < 128u) {
                for (int dx = -3; dx <= 3; dx++) {
                    int xx = px + dx;
                    if ((unsigned)xx < 128u) {
                        int p = yy * 128 + xx;
                        s += ny[p];
                        t += lt[p];
                    }
                }
            }
        }
        float tinv = __expf(-t * (1.0f / 49.0f));
        s_ab[tid] = make_float2(tinv, tinv * s);
    }
    for (int idx = tid; idx < 169 * 32; idx += 256) {
        int o = idx >> 5, p = idx & 31;
        s_lg[o * 34 + p] = lg[(size_t)o * HW + y0 + p]
                         + lg[(size_t)(169 + o) * HW + y0 + p];
    }
    __syncthreads();
    int pix = tid >> 3, t = tid & 7;
    int y = y0 + pix;
    float2 ab = s_ab[pix];
    float l[22];
#pragma unroll
    for (int j = 0; j < 22; j++) {
        int o = t + 8 * j;
        l[j] = (o < 169) ? -fmaf(ab.x, s_lg[o * 34 + pix], ab.y) : -3e38f;
    }
    u32 wp0[22], wp1[22], wp2[22], wp3[22];
#pragma unroll
    for (int j = 0; j < 22; j++) { wp0[j] = 0u; wp1[j] = 0u; wp2[j] = 0u; wp3[j] = 0u; }

    float e[22];
#pragma unroll
    for (int k = 0; k < 7; k++) {
        float m = -3e38f;
#pragma unroll
        for (int j = 0; j < 22; j++) m = fmaxf(m, l[j]);
        m = fmaxf(m, __shfl_xor(m, 1));
        m = fmaxf(m, __shfl_xor(m, 2));
        m = fmaxf(m, __shfl_xor(m, 4));
        float s = 0.f;
#pragma unroll
        for (int j = 0; j < 22; j++) { e[j] = __expf(l[j] - m); s += e[j]; }
        s += __shfl_xor(s, 1);
        s += __shfl_xor(s, 2);
        s += __shfl_xor(s, 4);
        float rs = 1.0f / s;
#pragma unroll
        for (int j = 0; j < 22; j++) {
            float w = e[j] * rs;
            u32 hh = (u32)f2h(w);
            if (k == 0) wp0[j] |= hh;
            else if (k == 1) wp0[j] |= hh << 16;
            else if (k == 2) wp1[j] |= hh;
            else if (k == 3) wp1[j] |= hh << 16;
            else if (k == 4) wp2[j] |= hh;
            else if (k == 5) wp2[j] |= hh << 16;
            else wp3[j] |= hh;
            if (k < 6) l[j] += __logf(fmaxf(1.0f - w, 1e-6f));
        }
    }
#pragma unroll
    for (int j = 0; j < 22; j++) {
        int o = t + 8 * j;
        if (o < 169)
            *reinterpret_cast<uint4*>(Wkt + ((size_t)o * HW + y) * 8) =
                make_uint4(wp0[j], wp1[j], wp2[j], wp3[j]);
    }
}

// ---------------------------------------------------------------------------
// K2b v4: 7x7 boxsum of Wkt(f16) -> PAIR-PACKED WsP[o2][y][8 u32].
// grid SWAPPED to (16 tiles, 91 o2): linear bid = tile + 16*o2 -> XCD =
// tile%8 for ALL o2 -> each image tile's 91 WsP planes live on ONE XCD's L2
// (consumed by the XCD-aligned k_agg). Sliding-window vert phase.
// ---------------------------------------------------------------------------
__global__ __launch_bounds__(256) void k_wsum(
        const u16* __restrict__ Wkt, u32* __restrict__ WsP) {
    __shared__ u16 s_w[38 * 39 * 8];   // [row][col pad39][k8]
    __shared__ u16 s_v[32 * 38 * 8];   // [outrow][col][k8] f16 vertical sums
    int o2 = blockIdx.y;
    int di = o2 / 7, djp = o2 - di * 7;
    int oA = di * 13 + 2 * djp;
    bool hasB = (djp < 6);
    int tile = blockIdx.x;
    int h0 = (tile >> 2) * 32, w0 = (tile & 3) * 32;
    int tid = threadIdx.x;

    auto stage = [&](int o) {
        const u16* src = Wkt + (size_t)o * (HW * 8);
        for (int idx = tid; idx < 38 * 38; idx += 256) {
            int r = idx / 38, c = idx - r * 38;
            int gy = h0 - 3 + r, gx = w0 - 3 + c;
            uint4 v = make_uint4(0u, 0u, 0u, 0u);
            if ((unsigned)gy < 128u && (unsigned)gx < 128u)
                v = *reinterpret_cast<const uint4*>(src + (gy * 128 + gx) * 8);
            *reinterpret_cast<uint4*>(s_w + (r * 39 + c) * 8) = v;
        }
    };
    auto vert = [&]() {
        for (int u = tid; u < 304; u += 256) {   // 8 groups(4 out-rows) x 38 cols
            int g = u / 38, c = u - g * 38;
            int r0 = g * 4;
            uint4 q[10];
#pragma unroll
            for (int d = 0; d < 10; d++)
                q[d] = *reinterpret_cast<const uint4*>(s_w + ((r0 + d) * 39 + c) * 8);
            uint4 s = q[0];
#pragma unroll
            for (int d = 1; d < 7; d++) {
                s.x = hadd2u(s.x, q[d].x); s.y = hadd2u(s.y, q[d].y);
                s.z = hadd2u(s.z, q[d].z); s.w = hadd2u(s.w, q[d].w);
            }
            *reinterpret_cast<uint4*>(s_v + (r0 * 38 + c) * 8) = s;
#pragma unroll
            for (int j = 1; j < 4; j++) {
                s.x = hadd2u(hsub2u(s.x, q[j - 1].x), q[j + 6].x);
                s.y = hadd2u(hsub2u(s.y, q[j - 1].y), q[j + 6].y);
                s.z = hadd2u(hsub2u(s.z, q[j - 1].z), q[j + 6].z);
                s.w = hadd2u(hsub2u(s.w, q[j - 1].w), q[j + 6].w);
                *reinterpret_cast<uint4*>(s_v + ((r0 + j) * 38 + c) * 8) = s;
            }
        }
    };
    auto horiz = [&](uint4 (&rr)[4]) {
#pragma unroll
        for (int i = 0; i < 4; i++) {              // 32 rows x 32 out-cols
            int u = tid + i * 256;
            int r = u >> 5, cx = u & 31;
            __half2 s0 = __builtin_bit_cast(__half2, 0u);
            __half2 s1 = s0, s2 = s0, s3 = s0;
#pragma unroll
            for (int d = 0; d < 7; d++) {
                uint4 q = *reinterpret_cast<const uint4*>(s_v + (r * 38 + cx + d) * 8);
                s0 = __hadd2(s0, __builtin_bit_cast(__half2, q.x));
                s1 = __hadd2(s1, __builtin_bit_cast(__half2, q.y));
                s2 = __hadd2(s2, __builtin_bit_cast(__half2, q.z));
                s3 = __hadd2(s3, __builtin_bit_cast(__half2, q.w));
            }
            rr[i] = make_uint4(
                __builtin_bit_cast(u32, s0), __builtin_bit_cast(u32, s1),
                __builtin_bit_cast(u32, s2), __builtin_bit_cast(u32, s3));
        }
    };

    uint4 rA[4], rB[4];
#pragma unroll
    for (int i = 0; i < 4; i++) rB[i] = make_uint4(0u, 0u, 0u, 0u);

    stage(oA);
    __syncthreads();
    vert();
    __syncthreads();
    horiz(rA);
    if (hasB) {
        __syncthreads();           // rA-horiz reads done; safe to overwrite s_w
        stage(oA + 1);
        __syncthreads();
        vert();
        __syncthreads();
        horiz(rB);
    }

#pragma unroll
    for (int i = 0; i < 4; i++) {
        int u = tid + i * 256;
        int r = u >> 5, cx = u & 31;
        int y = (h0 + r) * 128 + (w0 + cx);
        u32* dst = WsP + ((size_t)o2 * HW + y) * 8;
        uint4 lo = make_uint4(
            __builtin_amdgcn_perm(rB[i].x, rA[i].x, SELLO),
            __builtin_amdgcn_perm(rB[i].x, rA[i].x, SELHI),
            __builtin_amdgcn_perm(rB[i].y, rA[i].y, SELLO),
            __builtin_amdgcn_perm(rB[i].y, rA[i].y, SELHI));
        uint4 hi = make_uint4(
            __builtin_amdgcn_perm(rB[i].z, rA[i].z, SELLO),
            __builtin_amdgcn_perm(rB[i].z, rA[i].z, SELHI),
            __builtin_amdgcn_perm(rB[i].w, rA[i].w, SELLO),
            0u);
        *reinterpret_cast<uint4*>(dst) = lo;
        *reinterpret_cast<uint4*>(dst + 4) = hi;
    }
}

// ---------------------------------------------------------------------------
// K3 = v7 + XCD-aligned blockIdx remap: block of image-tile t2 runs on XCD
// t2%8, where k_wsum just wrote that tile's WsP planes -> L2 hits.
// grid 256 tiles (4x16 pix); 512 thr = 64 pix x 8 cc (8ch each).
// ---------------------------------------------------------------------------
__global__ __launch_bounds__(512, 2) void k_agg(
        const u16* __restrict__ xh, const u32* __restrict__ WsP,
        float* __restrict__ out) {
    __shared__ u16 s_x[64 * 16 * 32];   // [ch][r][c] f16, 64KB
    // bijective remap: lbid -> tb with t2(tb)%8 == lbid%8
    int lbid = blockIdx.x;
    int cls = lbid & 7, idx0 = lbid >> 3;
    int t2 = cls + 8 * (idx0 & 1);
    int j = idx0 >> 1;                  // 0..15
    int tr = t2 >> 2, tc2 = t2 & 3;
    int tb = ((tr << 3) + (j >> 1)) * 8 + (tc2 * 2 + (j & 1));
    int h0 = (tb >> 3) * 4, w0 = (tb & 7) * 16;
    int tid = threadIdx.x;

#pragma unroll
    for (int i = 0; i < 8; i++) {
        int it = tid + i * 512;
        int ch = it >> 6;
        int r = (it >> 2) & 15;
        int c0 = (it & 3) * 8;
        int gy = h0 - 6 + r, gx0 = w0 - 6 + c0;
        uint4 v = make_uint4(0u, 0u, 0u, 0u);
        if ((unsigned)gy < 128u) {
            const u16* src = xh + (size_t)ch * HW + gy * 128;
            if (gx0 >= 0 && gx0 <= 120) {
                v = *reinterpret_cast<const uint4*>(src + gx0);
            } else {
                auto pk = [&](int gx) -> u32 {
                    u32 lo = ((unsigned)gx < 128u) ? (u32)src[gx] : 0u;
                    u32 hi = ((unsigned)(gx + 1) < 128u) ? (u32)src[gx + 1] : 0u;
                    return lo | (hi << 16);
                };
                v = make_uint4(pk(gx0), pk(gx0 + 2), pk(gx0 + 4), pk(gx0 + 6));
            }
        }
        *reinterpret_cast<uint4*>(s_x + (ch * 16 + r) * 32 + c0) = v;
    }
    __syncthreads();

    int cc = tid >> 6, pix = tid & 63;
    int pr = pix >> 4, pc = pix & 15;
    int y = (h0 + pr) * 128 + (w0 + pc);
    const u32* wsrc = WsP + (size_t)y * 8;
    const u32* s_x32 = reinterpret_cast<const u32*>(s_x);
    u32 sh = (u32)(pc & 1) * 16;
    int base0 = cc * 8 * 256 + (pc >> 1);   // + q*256 + (pr+di)*16

    float acc[7][8];
#pragma unroll
    for (int k = 0; k < 7; k++)
#pragma unroll
        for (int q = 0; q < 8; q++) acc[k][q] = 0.f;

    auto loadW = [&](int di, uint4 (&A)[7], uint4 (&B)[7]) {
        const u32* wdi = wsrc + (size_t)(di * 7) * (HW * 8);
#pragma unroll
        for (int djp = 0; djp < 7; djp++) {
            const u32* wp = wdi + (size_t)djp * (HW * 8);
            A[djp] = *reinterpret_cast<const uint4*>(wp);
            B[djp] = *reinterpret_cast<const uint4*>(wp + 4);
        }
    };
    auto compute = [&](int di, const uint4 (&A)[7], const uint4 (&B)[7]) {
        int rowoff = (pr + di) * 16;
#pragma unroll
        for (int q = 0; q < 8; q++) {
            const u32* p = s_x32 + base0 + q * 256 + rowoff;
            u32 f0 = p[0], f1 = p[1], f2 = p[2], f3 = p[3];
            u32 f4 = p[4], f5 = p[5], f6 = p[6], f7 = p[7];
            u32 x2;
            x2 = __builtin_amdgcn_alignbit(f1, f0, sh);
            dot2acc(acc[0][q], A[0].x, x2); dot2acc(acc[1][q], A[0].y, x2);
            dot2acc(acc[2][q], A[0].z, x2); dot2acc(acc[3][q], A[0].w, x2);
            dot2acc(acc[4][q], B[0].x, x2); dot2acc(acc[5][q], B[0].y, x2);
            dot2acc(acc[6][q], B[0].z, x2);
            x2 = __builtin_amdgcn_alignbit(f2, f1, sh);
            dot2acc(acc[0][q], A[1].x, x2); dot2acc(acc[1][q], A[1].y, x2);
            dot2acc(acc[2][q], A[1].z, x2); dot2acc(acc[3][q], A[1].w, x2);
            dot2acc(acc[4][q], B[1].x, x2); dot2acc(acc[5][q], B[1].y, x2);
            dot2acc(acc[6][q], B[1].z, x2);
            x2 = __builtin_amdgcn_alignbit(f3, f2, sh);
            dot2acc(acc[0][q], A[2].x, x2); dot2acc(acc[1][q], A[2].y, x2);
            dot2acc(acc[2][q], A[2].z, x2); dot2acc(acc[3][q], A[2].w, x2);
            dot2acc(acc[4][q], B[2].x, x2); dot2acc(acc[5][q], B[2].y, x2);
            dot2acc(acc[6][q], B[2].z, x2);
            x2 = __builtin_amdgcn_alignbit(f4, f3, sh);
            dot2acc(acc[0][q], A[3].x, x2); dot2acc(acc[1][q], A[3].y, x2);
            dot2acc(acc[2][q], A[3].z, x2); dot2acc(acc[3][q], A[3].w, x2);
            dot2acc(acc[4][q], B[3].x, x2); dot2acc(acc[5][q], B[3].y, x2);
            dot2acc(acc[6][q], B[3].z, x2);
            x2 = __builtin_amdgcn_alignbit(f5, f4, sh);
            dot2acc(acc[0][q], A[4].x, x2); dot2acc(acc[1][q], A[4].y, x2);
            dot2acc(acc[2][q], A[4].z, x2); dot2acc(acc[3][q], A[4].w, x2);
            dot2acc(acc[4][q], B[4].x, x2); dot2acc(acc[5][q], B[4].y, x2);
            dot2acc(acc[6][q], B[4].z, x2);
            x2 = __builtin_amdgcn_alignbit(f6, f5, sh);
            dot2acc(acc[0][q], A[5].x, x2); dot2acc(acc[1][q], A[5].y, x2);
            dot2acc(acc[2][q], A[5].z, x2); dot2acc(acc[3][q], A[5].w, x2);
            dot2acc(acc[4][q], B[5].x, x2); dot2acc(acc[5][q], B[5].y, x2);
            dot2acc(acc[6][q], B[5].z, x2);
            x2 = __builtin_amdgcn_alignbit(f7, f6, sh);
            dot2acc(acc[0][q], A[6].x, x2); dot2acc(acc[1][q], A[6].y, x2);
            dot2acc(acc[2][q], A[6].z, x2); dot2acc(acc[3][q], A[6].w, x2);
            dot2acc(acc[4][q], B[6].x, x2); dot2acc(acc[5][q], B[6].y, x2);
            dot2acc(acc[6][q], B[6].z, x2);
        }
    };

    uint4 WA[7], WB[7], WC[7], WD[7];
    loadW(0, WA, WB);
#pragma unroll 1
    for (int di = 0; di < 12; di += 2) {
        loadW(di + 1, WC, WD);     // prefetch next di while computing current
        compute(di, WA, WB);
        loadW(di + 2, WA, WB);     // di+2 <= 12 always inside this loop
        compute(di + 1, WC, WD);
    }
    compute(12, WA, WB);

#pragma unroll
    for (int k = 0; k < 7; k++)
#pragma unroll
        for (int q = 0; q < 8; q++)
            out[(k * 64 + cc * 8 + q) * HW + y] = acc[k][q];
}

// ---------------------------------------------------------------------------
extern "C" void kernel_launch(void* const* d_in, const int* in_sizes, int n_in,
                              void* d_out, int out_size, void* d_ws, size_t ws_size,
                              hipStream_t stream) {
    (void)in_sizes; (void)n_in; (void)out_size; (void)ws_size;
    const float* x  = (const float*)d_in[0];
    const float* xe = (const float*)d_in[1];
    const float* ye = (const float*)d_in[2];
    const float* lt = (const float*)d_in[3];
    float* out = (float*)d_out;
    char* ws = (char*)d_ws;

    // layout (~121 MB). All disjoint.
    u16*    xh  = (u16*)(ws + 0);              //  2,097,152 B (f16 [64][128][128])
    float*  xeT = (float*)(ws + 2097152u);     //  2,097,152
    float*  yeT = (float*)(ws + 4194304u);     //  2,097,152
    u16*    Wkt = (u16*)(ws + 6291456u);       // 44,302,336 -> 50,593,792
    float*  lg  = (float*)(ws + 50593792u);    // 22,151,168 -> 72,744,960
    u32*    WsP = (u32*)(ws + 72744960u);      // 47,710,208 -> 120,455,168
    float*  nx2 = (float*)(ws + 120455168u);   //    131,072
    float*  ny  = (float*)(ws + 120586240u);   //     65,536 -> ends 120,651,776

    k_prep<<<256, 256, 0, stream>>>(x, xe, ye, xh, xeT, yeT, nx2, ny);
    k_logits<<<dim3(13, 64, 2), 1024, 0, stream>>>(xeT, yeT, nx2, lg);
    k_softmax<<<512, 256, 0, stream>>>(lg, ny, lt, Wkt);
    k_wsum<<<dim3(16, 91), 256, 0, stream>>>(Wkt, WsP);
    k_agg<<<256, 512, 0, stream>>>(xh, WsP, out);
}